// Round 5
// baseline (639.912 us; speedup 1.0000x reference)
//
#include <hip/hip_runtime.h>
#include <hip/hip_bf16.h>
#include <stdint.h>

#define S_LEN 4096
#define HID 2048
#define NH 16
#define KVH 8
#define DH 128
#define EPS 1e-6f
#define SCALE 0.08838834764831845f  // 128^-0.5

typedef __bf16 bf16x8 __attribute__((ext_vector_type(8)));
typedef __bf16 bf16x4 __attribute__((ext_vector_type(4)));
typedef float f32x4 __attribute__((ext_vector_type(4)));

// Async global->LDS, 16B per lane. LDS dest must be wave-uniform base;
// lane i lands at dst + i*16B (m97/m104-verified semantics).
__device__ inline void gl_lds16(const __bf16* g, __bf16* l) {
  __builtin_amdgcn_global_load_lds(
      (const __attribute__((address_space(1))) void*)g,
      (__attribute__((address_space(3))) void*)l, 16, 0, 0);
}

// ---------------------------------------------------------------------------
// fp32 -> bf16 bulk convert (4 elems/thread).
// ---------------------------------------------------------------------------
__global__ __launch_bounds__(256) void f2b4(
    const float* __restrict__ in, __bf16* __restrict__ out, int n4) {
  int i = blockIdx.x * 256 + threadIdx.x;
  if (i < n4) {
    float4 v = ((const float4*)in)[i];
    bf16x4 o;
    o[0] = (__bf16)v.x; o[1] = (__bf16)v.y; o[2] = (__bf16)v.z; o[3] = (__bf16)v.w;
    ((bf16x4*)out)[i] = o;
  }
}

// ---------------------------------------------------------------------------
// m97-structure NT GEMM: C(MxN) = A(MxK)@B(NxK)^T + bias. A,B bf16; C dtype TC.
// 128x128 block tile, BK=32, 4 waves (2x2), 16 MFMA/wave/K-step.
// bias_mode: 0 none, 1 per-col, 2 per-row.
// ---------------------------------------------------------------------------
template <typename TC>
__global__ __launch_bounds__(256) void gemm128(
    const __bf16* __restrict__ A, const __bf16* __restrict__ B,
    const float* __restrict__ bias, TC* __restrict__ C,
    int N, int K, int bias_mode)
{
  __shared__ __attribute__((aligned(16))) __bf16 As[128 * 32];
  __shared__ __attribute__((aligned(16))) __bf16 Bs[128 * 32];
  const int wave = threadIdx.x >> 6, lane = threadIdx.x & 63;
  const int quad = lane >> 4, l16 = lane & 15;
  const int wm = wave >> 1, wn = wave & 1;
  const int m0 = blockIdx.y * 128, n0 = blockIdx.x * 128;
  const int srow = lane >> 2, scol = (lane & 3) * 8;  // staging lane map

  f32x4 acc[4][4] = {};

  for (int k0 = 0; k0 < K; k0 += 32) {
    __syncthreads();  // previous iter's reads done before overwrite
#pragma unroll
    for (int j = wave; j < 8; j += 4) {   // j wave-uniform
      gl_lds16(A + (size_t)(m0 + j * 16 + srow) * K + k0 + scol, As + j * 512);
      gl_lds16(B + (size_t)(n0 + j * 16 + srow) * K + k0 + scol, Bs + j * 512);
    }
    __syncthreads();  // drains vmcnt before barrier (compiler-enforced)
    bf16x8 af[4], bfr[4];
#pragma unroll
    for (int s = 0; s < 4; ++s) {
      af[s]  = *(const bf16x8*)(As + (wm * 64 + s * 16 + l16) * 32 + quad * 8);
      bfr[s] = *(const bf16x8*)(Bs + (wn * 64 + s * 16 + l16) * 32 + quad * 8);
    }
#pragma unroll
    for (int ms = 0; ms < 4; ++ms)
#pragma unroll
      for (int ns = 0; ns < 4; ++ns)
        acc[ms][ns] = __builtin_amdgcn_mfma_f32_16x16x32_bf16(
            af[ms], bfr[ns], acc[ms][ns], 0, 0, 0);
  }

#pragma unroll
  for (int ms = 0; ms < 4; ++ms)
#pragma unroll
    for (int ns = 0; ns < 4; ++ns)
#pragma unroll
      for (int r = 0; r < 4; ++r) {
        int row = m0 + wm * 64 + ms * 16 + quad * 4 + r;
        int col = n0 + wn * 64 + ns * 16 + l16;
        float v = acc[ms][ns][r];
        if (bias_mode == 1) v += bias[col];
        else if (bias_mode == 2) v += bias[row];
        C[(size_t)row * N + col] = (TC)v;
      }
}

// ---------------------------------------------------------------------------
// Per-head RMSNorm (D=128) + RoPE, in-place on q,k (bf16). One wave/(s,head).
// SCALE (1/sqrt(D)) folded into q output so attn skips the per-score scale.
// ---------------------------------------------------------------------------
__global__ __launch_bounds__(256) void rmsnorm_rope(
    __bf16* __restrict__ q, __bf16* __restrict__ k,
    const float* __restrict__ cosb, const float* __restrict__ sinb,
    const float* __restrict__ qw, const float* __restrict__ kw)
{
  const int wave = threadIdx.x >> 6;
  const int lane = threadIdx.x & 63;
  const int row = blockIdx.x * 4 + wave;
  const int s   = row / (NH + KVH);
  const int idx = row % (NH + KVH);

  __bf16* base;
  const float* w;
  float oscale;
  if (idx < NH) { base = q + ((size_t)s * NH + idx) * DH;         w = qw; oscale = SCALE; }
  else          { base = k + ((size_t)s * KVH + (idx - NH)) * DH; w = kw; oscale = 1.0f; }

  float x1 = (float)base[lane];
  float x2 = (float)base[lane + 64];
  float ss = x1 * x1 + x2 * x2;
#pragma unroll
  for (int m = 1; m < 64; m <<= 1) ss += __shfl_xor(ss, m, 64);
  float inv = rsqrtf(ss * (1.0f / 128.0f) + EPS);

  float xh1 = x1 * inv * w[lane];
  float xh2 = x2 * inv * w[lane + 64];
  const float* cs = cosb + (size_t)s * DH;
  const float* sn = sinb + (size_t)s * DH;
  base[lane]      = (__bf16)((xh1 * cs[lane]      - xh2 * sn[lane])      * oscale);
  base[lane + 64] = (__bf16)((xh2 * cs[lane + 64] + xh1 * sn[lane + 64]) * oscale);
}

// ---------------------------------------------------------------------------
// Flash attention v6 = R4's verified structure + occupancy/VALU fixes.
// Causal, GQA reps=2. Grid (64, NH) = 1024 blocks, block 256 (4 waves),
// ONE q-tile per block, qt = 63-bx (biggest first for greedy balance).
// R4 post-mortem: 512-block grid capped residency at 2 blocks/CU (grid-,
// not LDS-limited; LDS 41KB fits 3). 1024 blocks -> 3/CU = 12 waves/CU.
//  - Ks/Vs XOR-swizzled both sides (rule #21) - R4-verified (8.6e7->9.6e6).
//  - causal mask only on diagonal tile; SCALE pre-folded into q.
//  - T13 defer-max (THR=8): skip row-max reduce + rescale on most tiles.
//  - NEW: lrun kept as per-lane PARTIAL sum (alpha is uniform within each
//    16-lane group, so rescale of partials is valid); single 16-lane
//    shfl-reduce at epilogue. Removes 16 serial shfl+add per lane-tile.
// R3 lessons: NO V-in-registers, NO launch_bounds min-waves (spill).
// ---------------------------------------------------------------------------
__global__ __launch_bounds__(256) void attn2(
    const __bf16* __restrict__ q,   // S x NH x DH  (pre-scaled by SCALE)
    const __bf16* __restrict__ k,   // S x KVH x DH
    const __bf16* __restrict__ vt,  // KVH x DH x S
    __bf16* __restrict__ o)         // S x NH x DH
{
  __shared__ __attribute__((aligned(16))) __bf16 Ks[64 * DH];   // 16KB swz
  __shared__ __attribute__((aligned(16))) __bf16 Vs[DH * 64];   // 16KB swz
  __shared__ __attribute__((aligned(16))) __bf16 pl[4][16 * 72];// 9KB
  const int wave = threadIdx.x >> 6, lane = threadIdx.x & 63;
  const int quad = lane >> 4, l16 = lane & 15;
  const int h = blockIdx.y, kvh = h >> 1;
  const int qt = 63 - (int)blockIdx.x;   // biggest q-tiles dispatch first
  const int qbase = qt * 64 + wave * 16;

  const __bf16* kh = k + (size_t)kvh * DH;           // row s at + s*KVH*DH
  const __bf16* vh = vt + (size_t)kvh * DH * S_LEN;  // row d at + d*S_LEN

  bf16x8 qa[4];
  const __bf16* qrow = q + ((size_t)(qbase + l16) * NH + h) * DH + quad * 8;
#pragma unroll
  for (int c = 0; c < 4; ++c) qa[c] = *(const bf16x8*)(qrow + c * 32);

  f32x4 oacc[8] = {};
  float mrun[4], lrun[4];   // lrun = per-lane PARTIAL row-sum (reduced at end)
#pragma unroll
  for (int r = 0; r < 4; ++r) { mrun[r] = -3.0e38f; lrun[r] = 0.0f; }

  for (int kt = 0; kt <= qt; ++kt) {
    const int k0 = kt * 64;
    __syncthreads();  // all waves done with previous tile's LDS
    // stage K rows k0..k0+63 (global col pre-swizzled; LDS dest linear)
#pragma unroll
    for (int j = wave; j < 16; j += 4) {
      int r  = j * 4 + (lane >> 4);
      int cb = ((lane & 15) * 16) ^ ((r & 7) << 4);
      gl_lds16(kh + (size_t)(k0 + r) * (KVH * DH) + (cb >> 1), Ks + j * 512);
    }
    // stage V^T rows (d), cols k0..k0+63 (global col pre-swizzled)
#pragma unroll
    for (int j = wave; j < 16; j += 4) {
      int d  = j * 8 + (lane >> 3);
      int cb = ((lane & 7) * 16) ^ ((d & 7) << 4);
      gl_lds16(vh + (size_t)d * S_LEN + k0 + (cb >> 1), Vs + j * 512);
    }
    __syncthreads();  // drains global_load_lds (vmcnt) + barrier

    // ---- scores: 4 col-subtiles x 4 d-chunks (swizzled ds_read) ----
    f32x4 sc[4] = {};
#pragma unroll
    for (int tt = 0; tt < 4; ++tt) {
      const int row = tt * 16 + l16;
      const int swz = (row & 7) << 4;
#pragma unroll
      for (int c = 0; c < 4; ++c) {
        bf16x8 bk = *(const bf16x8*)(
            (const char*)Ks + row * 256 + ((c * 64 + quad * 16) ^ swz));
        sc[tt] = __builtin_amdgcn_mfma_f32_16x16x32_bf16(qa[c], bk, sc[tt], 0, 0, 0);
      }
    }
    // ---- causal mask: only the diagonal tile needs it (SCALE pre-folded) --
    if (kt == qt) {
#pragma unroll
      for (int tt = 0; tt < 4; ++tt)
#pragma unroll
        for (int r = 0; r < 4; ++r) {
          int col = k0 + tt * 16 + l16;
          int row = qbase + quad * 4 + r;
          if (col > row) sc[tt][r] = -3.0e38f;
        }
    }
    // ---- online softmax: T13 defer-max + deferred l-reduce ----
    float pmax[4];
    bool defer = true;
#pragma unroll
    for (int r = 0; r < 4; ++r) {
      float mx = fmaxf(fmaxf(sc[0][r], sc[1][r]), fmaxf(sc[2][r], sc[3][r]));
      pmax[r] = mx;
      defer = defer && (mx - mrun[r] <= 8.0f);
    }
    if (__all(defer)) {
      // keep old max: P bounded by e^8; no reduce, no rescale
#pragma unroll
      for (int r = 0; r < 4; ++r) {
        float s0 = __expf(sc[0][r] - mrun[r]);
        float s1 = __expf(sc[1][r] - mrun[r]);
        float s2 = __expf(sc[2][r] - mrun[r]);
        float s3 = __expf(sc[3][r] - mrun[r]);
        sc[0][r] = s0; sc[1][r] = s1; sc[2][r] = s2; sc[3][r] = s3;
        lrun[r] += (s0 + s1) + (s2 + s3);   // per-lane partial
      }
    } else {
#pragma unroll
      for (int r = 0; r < 4; ++r) {
        float mx = pmax[r];
#pragma unroll
        for (int msk = 1; msk < 16; msk <<= 1) mx = fmaxf(mx, __shfl_xor(mx, msk, 64));
        float mnew = fmaxf(mrun[r], mx);     // uniform within 16-lane group
        float sum = 0.0f;
#pragma unroll
        for (int tt = 0; tt < 4; ++tt) {
          float p = __expf(sc[tt][r] - mnew);
          sc[tt][r] = p;
          sum += p;
        }
        float alpha = __expf(mrun[r] - mnew);  // uniform -> partial-scale ok
        lrun[r] = lrun[r] * alpha + sum;
        mrun[r] = mnew;
#pragma unroll
        for (int c = 0; c < 8; ++c) oacc[c][r] *= alpha;
      }
    }
    // ---- P: C-layout -> A-layout via per-wave slab (stride 72) ----
#pragma unroll
    for (int tt = 0; tt < 4; ++tt)
#pragma unroll
      for (int r = 0; r < 4; ++r)
        pl[wave][(quad * 4 + r) * 72 + tt * 16 + l16] = (__bf16)sc[tt][r];
    bf16x8 pa[2];
#pragma unroll
    for (int kc = 0; kc < 2; ++kc)
      pa[kc] = *(const bf16x8*)(pl[wave] + l16 * 72 + kc * 32 + quad * 8);
    // ---- PV: 8 d-chunks x 2 k-chunks (swizzled ds_read) ----
#pragma unroll
    for (int c = 0; c < 8; ++c)
#pragma unroll
      for (int kc = 0; kc < 2; ++kc) {
        const int d = c * 16 + l16;
        bf16x8 bv = *(const bf16x8*)(
            (const char*)Vs + d * 128 + ((kc * 64 + quad * 16) ^ ((d & 7) << 4)));
        oacc[c] = __builtin_amdgcn_mfma_f32_16x16x32_bf16(pa[kc], bv, oacc[c], 0, 0, 0);
      }
  }

  // ---- epilogue: single l-reduce across the 16-lane group, then store ----
#pragma unroll
  for (int r = 0; r < 4; ++r) {
#pragma unroll
    for (int msk = 1; msk < 16; msk <<= 1) lrun[r] += __shfl_xor(lrun[r], msk, 64);
    lrun[r] = 1.0f / lrun[r];
  }
#pragma unroll
  for (int c = 0; c < 8; ++c)
#pragma unroll
    for (int r = 0; r < 4; ++r) {
      int row = qbase + quad * 4 + r;
      o[((size_t)row * NH + h) * DH + c * 16 + l16] = (__bf16)(oacc[c][r] * lrun[r]);
    }
}

// ---------------------------------------------------------------------------
extern "C" void kernel_launch(void* const* d_in, const int* in_sizes, int n_in,
                              void* d_out, int out_size, void* d_ws, size_t ws_size,
                              hipStream_t stream) {
  const float* x    = (const float*)d_in[0];
  const float* cosb = (const float*)d_in[1];
  const float* sinb = (const float*)d_in[2];
  // d_in[3] = mask (causal, reimplemented)
  const float* Wq  = (const float*)d_in[4];
  const float* bq  = (const float*)d_in[5];
  const float* Wk  = (const float*)d_in[6];
  const float* bk  = (const float*)d_in[7];
  const float* Wv  = (const float*)d_in[8];
  const float* bv  = (const float*)d_in[9];
  const float* Wo  = (const float*)d_in[10];
  const float* qnw = (const float*)d_in[11];
  const float* knw = (const float*)d_in[12];
  float* out = (float*)d_out;  // 4096x2048 fp32

  // ws (48 MB peak):
  char* ws = (char*)d_ws;
  __bf16* xb    = (__bf16*)(ws);                // 16 MB x bf16 (dies after v-GEMM)
  __bf16* Wqb   = (__bf16*)(ws + (16u << 20));  //  8 MB        (dies after q-GEMM)
  __bf16* Wkb   = (__bf16*)(ws + (24u << 20));  //  4 MB
  __bf16* Wvb   = (__bf16*)(ws + (28u << 20));  //  4 MB
  __bf16* kbuf  = (__bf16*)(ws + (32u << 20));  //  8 MB S x KVH x DH
  __bf16* vtbuf = (__bf16*)(ws + (40u << 20));  //  8 MB KVH x DH x S
  __bf16* Wob   = (__bf16*)(ws + (16u << 20));  //  8 MB (reuses Wqb slot)
  __bf16* ao    = (__bf16*)(ws);                // 16 MB attn out (reuses xb slot)
  // d_out doubles as scratch until the final GEMM:
  __bf16* qbuf = (__bf16*)d_out;                // 16 MB S x NH x DH

  dim3 blk(256);
  // fp32 -> bf16 converts
  f2b4<<<dim3(8192), blk, 0, stream>>>(x,  xb,  2097152);
  f2b4<<<dim3(4096), blk, 0, stream>>>(Wq, Wqb, 1048576);
  f2b4<<<dim3(2048), blk, 0, stream>>>(Wk, Wkb, 524288);
  f2b4<<<dim3(2048), blk, 0, stream>>>(Wv, Wvb, 524288);
  // q = x@Wq^T + bq  (4096x2048)
  gemm128<__bf16><<<dim3(16, 32), blk, 0, stream>>>(xb, Wqb, bq, qbuf, HID, HID, 1);
  // k = x@Wk^T + bk  (4096x1024)
  gemm128<__bf16><<<dim3(8, 32), blk, 0, stream>>>(xb, Wkb, bk, kbuf, KVH * DH, HID, 1);
  // v^T = Wv@x^T + bv[row]  (1024x4096)
  gemm128<__bf16><<<dim3(32, 8), blk, 0, stream>>>(Wvb, xb, bv, vtbuf, S_LEN, HID, 2);
  // rmsnorm + rope (in place; folds SCALE into q)
  rmsnorm_rope<<<dim3(S_LEN * (NH + KVH) / 4), blk, 0, stream>>>(
      qbuf, kbuf, cosb, sinb, qnw, knw);
  // Wo convert into dead Wqb slot (before attn so it overlaps the tail)
  f2b4<<<dim3(4096), blk, 0, stream>>>(Wo, Wob, 1048576);
  // attention -> ao (directly into dead xb slot; no memcpy)
  attn2<<<dim3(64, NH), blk, 0, stream>>>(qbuf, kbuf, vtbuf, ao);
  // out = ao @ Wo^T  (4096x2048, fp32 epilogue into full d_out)
  gemm128<float><<<dim3(16, 32), blk, 0, stream>>>(ao, Wob, nullptr, out, HID, HID, 0);
}

// Round 6
// 541.719 us; speedup vs baseline: 1.1813x; 1.1813x over previous
//
#include <hip/hip_runtime.h>
#include <hip/hip_bf16.h>
#include <stdint.h>

#define S_LEN 4096
#define HID 2048
#define NH 16
#define KVH 8
#define DH 128
#define EPS 1e-6f
#define SCALE 0.08838834764831845f  // 128^-0.5
#define LOG2E 1.4426950408889634f

#if __has_builtin(__builtin_amdgcn_exp2f)
#define EXP2(x) __builtin_amdgcn_exp2f(x)
#else
#define EXP2(x) exp2f(x)
#endif

typedef __bf16 bf16x8 __attribute__((ext_vector_type(8)));
typedef __bf16 bf16x4 __attribute__((ext_vector_type(4)));
typedef float f32x4 __attribute__((ext_vector_type(4)));

// Async global->LDS, 16B per lane. LDS dest must be wave-uniform base;
// lane i lands at dst + i*16B (m97/m104-verified semantics).
__device__ inline void gl_lds16(const __bf16* g, __bf16* l) {
  __builtin_amdgcn_global_load_lds(
      (const __attribute__((address_space(1))) void*)g,
      (__attribute__((address_space(3))) void*)l, 16, 0, 0);
}

// ---------------------------------------------------------------------------
// fp32 -> bf16 bulk convert (4 elems/thread).
// ---------------------------------------------------------------------------
__global__ __launch_bounds__(256) void f2b4(
    const float* __restrict__ in, __bf16* __restrict__ out, int n4) {
  int i = blockIdx.x * 256 + threadIdx.x;
  if (i < n4) {
    float4 v = ((const float4*)in)[i];
    bf16x4 o;
    o[0] = (__bf16)v.x; o[1] = (__bf16)v.y; o[2] = (__bf16)v.z; o[3] = (__bf16)v.w;
    ((bf16x4*)out)[i] = o;
  }
}

// ---------------------------------------------------------------------------
// m97-structure NT GEMM: C(MxN) = A(MxK)@B(NxK)^T + bias. A,B bf16; C dtype TC.
// 128x128 block tile, BK=32, 4 waves (2x2), 16 MFMA/wave/K-step.
// bias_mode: 0 none, 1 per-col, 2 per-row.
// ---------------------------------------------------------------------------
template <typename TC>
__global__ __launch_bounds__(256) void gemm128(
    const __bf16* __restrict__ A, const __bf16* __restrict__ B,
    const float* __restrict__ bias, TC* __restrict__ C,
    int N, int K, int bias_mode)
{
  __shared__ __attribute__((aligned(16))) __bf16 As[128 * 32];
  __shared__ __attribute__((aligned(16))) __bf16 Bs[128 * 32];
  const int wave = threadIdx.x >> 6, lane = threadIdx.x & 63;
  const int quad = lane >> 4, l16 = lane & 15;
  const int wm = wave >> 1, wn = wave & 1;
  const int m0 = blockIdx.y * 128, n0 = blockIdx.x * 128;
  const int srow = lane >> 2, scol = (lane & 3) * 8;  // staging lane map

  f32x4 acc[4][4] = {};

  for (int k0 = 0; k0 < K; k0 += 32) {
    __syncthreads();  // previous iter's reads done before overwrite
#pragma unroll
    for (int j = wave; j < 8; j += 4) {   // j wave-uniform
      gl_lds16(A + (size_t)(m0 + j * 16 + srow) * K + k0 + scol, As + j * 512);
      gl_lds16(B + (size_t)(n0 + j * 16 + srow) * K + k0 + scol, Bs + j * 512);
    }
    __syncthreads();  // drains vmcnt before barrier (compiler-enforced)
    bf16x8 af[4], bfr[4];
#pragma unroll
    for (int s = 0; s < 4; ++s) {
      af[s]  = *(const bf16x8*)(As + (wm * 64 + s * 16 + l16) * 32 + quad * 8);
      bfr[s] = *(const bf16x8*)(Bs + (wn * 64 + s * 16 + l16) * 32 + quad * 8);
    }
#pragma unroll
    for (int ms = 0; ms < 4; ++ms)
#pragma unroll
      for (int ns = 0; ns < 4; ++ns)
        acc[ms][ns] = __builtin_amdgcn_mfma_f32_16x16x32_bf16(
            af[ms], bfr[ns], acc[ms][ns], 0, 0, 0);
  }

#pragma unroll
  for (int ms = 0; ms < 4; ++ms)
#pragma unroll
    for (int ns = 0; ns < 4; ++ns)
#pragma unroll
      for (int r = 0; r < 4; ++r) {
        int row = m0 + wm * 64 + ms * 16 + quad * 4 + r;
        int col = n0 + wn * 64 + ns * 16 + l16;
        float v = acc[ms][ns][r];
        if (bias_mode == 1) v += bias[col];
        else if (bias_mode == 2) v += bias[row];
        C[(size_t)row * N + col] = (TC)v;
      }
}

// ---------------------------------------------------------------------------
// Per-head RMSNorm (D=128) + RoPE, in-place on q,k (bf16). One wave/(s,head).
// SCALE*LOG2E folded into q output: attn scores land in log2 domain so
// softmax uses raw v_exp_f32 (2^x) with no per-element multiply.
// ---------------------------------------------------------------------------
__global__ __launch_bounds__(256) void rmsnorm_rope(
    __bf16* __restrict__ q, __bf16* __restrict__ k,
    const float* __restrict__ cosb, const float* __restrict__ sinb,
    const float* __restrict__ qw, const float* __restrict__ kw)
{
  const int wave = threadIdx.x >> 6;
  const int lane = threadIdx.x & 63;
  const int row = blockIdx.x * 4 + wave;
  const int s   = row / (NH + KVH);
  const int idx = row % (NH + KVH);

  __bf16* base;
  const float* w;
  float oscale;
  if (idx < NH) { base = q + ((size_t)s * NH + idx) * DH;         w = qw; oscale = SCALE * LOG2E; }
  else          { base = k + ((size_t)s * KVH + (idx - NH)) * DH; w = kw; oscale = 1.0f; }

  float x1 = (float)base[lane];
  float x2 = (float)base[lane + 64];
  float ss = x1 * x1 + x2 * x2;
#pragma unroll
  for (int m = 1; m < 64; m <<= 1) ss += __shfl_xor(ss, m, 64);
  float inv = rsqrtf(ss * (1.0f / 128.0f) + EPS);

  float xh1 = x1 * inv * w[lane];
  float xh2 = x2 * inv * w[lane + 64];
  const float* cs = cosb + (size_t)s * DH;
  const float* sn = sinb + (size_t)s * DH;
  base[lane]      = (__bf16)((xh1 * cs[lane]      - xh2 * sn[lane])      * oscale);
  base[lane + 64] = (__bf16)((xh2 * cs[lane + 64] + xh1 * sn[lane + 64]) * oscale);
}

// ---------------------------------------------------------------------------
// Flash attention v7 = R4's verified paired structure (180us) + per-tile
// critical-path cuts. Causal, GQA reps=2. Grid (32, NH), block 256 (4 waves),
// triangle pairing {bx, 63-bx} -> uniform 65 k-tiles/block (R5 proved
// un-pairing -> straggler tail -> 263us; occupancy is capped at 8 waves/CU
// in this family, so attack the serial chain instead).
//  - NEW: double-buffered K/V with T3-minimum prefetch: issue tile kt+1's
//    global_load_lds BEFORE computing tile kt; ONE barrier/tile (was 2).
//    The compiler's vmcnt(0)-before-barrier now drains a prefetch that had
//    a full compute phase to land -> stage-drain stall ~0. LDS 74.75KB,
//    2 blocks/CU unchanged (grid-limited).
//  - NEW: exp2-domain softmax (LOG2E pre-folded into q): deletes the v_mul
//    inside every __expf. Defer threshold 8 in log2 units (P <= 256).
//  - NEW: staging lane-offsets hoisted out of k-loop (static unroll).
//  - R4-verified: both-sides XOR swizzle on Ks/Vs; diagonal-only mask.
//  - R5-verified: per-lane partial lrun, single epilogue reduce.
// R3 lessons: NO V-in-registers, NO launch_bounds min-waves (spill).
// ---------------------------------------------------------------------------
__global__ __launch_bounds__(256) void attn2(
    const __bf16* __restrict__ q,   // S x NH x DH  (pre-scaled by SCALE*LOG2E)
    const __bf16* __restrict__ k,   // S x KVH x DH
    const __bf16* __restrict__ vt,  // KVH x DH x S
    __bf16* __restrict__ o)         // S x NH x DH
{
  __shared__ __attribute__((aligned(16))) __bf16 Ks[2][64 * DH];  // 32KB swz
  __shared__ __attribute__((aligned(16))) __bf16 Vs[2][DH * 64];  // 32KB swz
  __shared__ __attribute__((aligned(16))) __bf16 pl[4][16 * 72];  // 9KB
  const int wave = threadIdx.x >> 6, lane = threadIdx.x & 63;
  const int quad = lane >> 4, l16 = lane & 15;
  const int h = blockIdx.y, kvh = h >> 1;

  const __bf16* kh = k + (size_t)kvh * DH;           // row s at + s*KVH*DH
  const __bf16* vh = vt + (size_t)kvh * DH * S_LEN;  // row d at + d*S_LEN

  // Loop-invariant staging lane offsets (4 K-issues + 4 V-issues per wave).
  int krow[4], kcol[4], vrow[4], vcol[4];
#pragma unroll
  for (int i = 0; i < 4; ++i) {
    int j = wave + i * 4;
    int r = j * 4 + (lane >> 4);
    int cbK = ((lane & 15) * 16) ^ ((r & 7) << 4);
    krow[i] = r; kcol[i] = cbK >> 1;
    int d = j * 8 + (lane >> 3);
    int cbV = ((lane & 7) * 16) ^ ((d & 7) << 4);
    vrow[i] = d; vcol[i] = cbV >> 1;
  }
  // Stage k-tile (rows/cols k0..k0+63) into buffer buf. LDS dest linear;
  // XOR-swizzle applied to GLOBAL source col (rule #21 both-sides).
  auto stage = [&](int buf, int k0) {
#pragma unroll
    for (int i = 0; i < 4; ++i)
      gl_lds16(kh + (size_t)(k0 + krow[i]) * (KVH * DH) + kcol[i],
               &Ks[buf][(wave + i * 4) * 512]);
#pragma unroll
    for (int i = 0; i < 4; ++i)
      gl_lds16(vh + (size_t)vrow[i] * S_LEN + k0 + vcol[i],
               &Vs[buf][(wave + i * 4) * 512]);
  };

  for (int phase = 0; phase < 2; ++phase) {
    const int qt = phase == 0 ? (int)blockIdx.x : 63 - (int)blockIdx.x;
    const int qbase = qt * 64 + wave * 16;

    bf16x8 qa[4];
    const __bf16* qrow = q + ((size_t)(qbase + l16) * NH + h) * DH + quad * 8;
#pragma unroll
    for (int c = 0; c < 4; ++c) qa[c] = *(const bf16x8*)(qrow + c * 32);

    f32x4 oacc[8] = {};
    float mrun[4], lrun[4];  // lrun = per-lane PARTIAL row-sum
#pragma unroll
    for (int r = 0; r < 4; ++r) { mrun[r] = -3.0e38f; lrun[r] = 0.0f; }

    __syncthreads();   // prev phase's last reads done before restage
    stage(0, 0);       // prologue

    for (int kt = 0; kt <= qt; ++kt) {
      const int cur = kt & 1;
      const int k0 = kt * 64;
      // Single barrier/tile: own vmcnt(0) drain (compiler-enforced) makes
      // buf[cur] visible; also separates prev iter's buf[cur^1] reads from
      // the restage below.
      __syncthreads();
      if (kt < qt) stage(cur ^ 1, k0 + 64);  // prefetch flies over compute

      const char* ksb = (const char*)Ks[cur];
      const char* vsb = (const char*)Vs[cur];

      // ---- scores: 4 col-subtiles x 4 d-chunks (swizzled ds_read) ----
      f32x4 sc[4] = {};
#pragma unroll
      for (int tt = 0; tt < 4; ++tt) {
        const int row = tt * 16 + l16;
        const int swz = (row & 7) << 4;
#pragma unroll
        for (int c = 0; c < 4; ++c) {
          bf16x8 bk = *(const bf16x8*)(ksb + row * 256 + ((c * 64 + quad * 16) ^ swz));
          sc[tt] = __builtin_amdgcn_mfma_f32_16x16x32_bf16(qa[c], bk, sc[tt], 0, 0, 0);
        }
      }
      // ---- causal mask: only the diagonal tile ----
      if (kt == qt) {
#pragma unroll
        for (int tt = 0; tt < 4; ++tt)
#pragma unroll
          for (int r = 0; r < 4; ++r) {
            int col = k0 + tt * 16 + l16;
            int row = qbase + quad * 4 + r;
            if (col > row) sc[tt][r] = -3.0e38f;
          }
      }
      // ---- online softmax (log2 domain): T13 defer-max + deferred l-reduce --
      float pmax[4];
      bool defer = true;
#pragma unroll
      for (int r = 0; r < 4; ++r) {
        float mx = fmaxf(fmaxf(sc[0][r], sc[1][r]), fmaxf(sc[2][r], sc[3][r]));
        pmax[r] = mx;
        defer = defer && (mx - mrun[r] <= 8.0f);
      }
      if (__all(defer)) {
        // keep old max: P bounded by 2^8; no reduce, no rescale
#pragma unroll
        for (int r = 0; r < 4; ++r) {
          float s0 = EXP2(sc[0][r] - mrun[r]);
          float s1 = EXP2(sc[1][r] - mrun[r]);
          float s2 = EXP2(sc[2][r] - mrun[r]);
          float s3 = EXP2(sc[3][r] - mrun[r]);
          sc[0][r] = s0; sc[1][r] = s1; sc[2][r] = s2; sc[3][r] = s3;
          lrun[r] += (s0 + s1) + (s2 + s3);   // per-lane partial
        }
      } else {
#pragma unroll
        for (int r = 0; r < 4; ++r) {
          float mx = pmax[r];
#pragma unroll
          for (int msk = 1; msk < 16; msk <<= 1) mx = fmaxf(mx, __shfl_xor(mx, msk, 64));
          float mnew = fmaxf(mrun[r], mx);     // uniform within 16-lane group
          float sum = 0.0f;
#pragma unroll
          for (int tt = 0; tt < 4; ++tt) {
            float p = EXP2(sc[tt][r] - mnew);
            sc[tt][r] = p;
            sum += p;
          }
          float alpha = EXP2(mrun[r] - mnew);  // uniform -> partial-scale ok
          lrun[r] = lrun[r] * alpha + sum;
          mrun[r] = mnew;
#pragma unroll
          for (int c = 0; c < 8; ++c) oacc[c][r] *= alpha;
        }
      }
      // ---- P: C-layout -> A-layout via per-wave slab (stride 72) ----
#pragma unroll
      for (int tt = 0; tt < 4; ++tt)
#pragma unroll
        for (int r = 0; r < 4; ++r)
          pl[wave][(quad * 4 + r) * 72 + tt * 16 + l16] = (__bf16)sc[tt][r];
      bf16x8 pa[2];
#pragma unroll
      for (int kc = 0; kc < 2; ++kc)
        pa[kc] = *(const bf16x8*)(pl[wave] + l16 * 72 + kc * 32 + quad * 8);
      // ---- PV: 8 d-chunks x 2 k-chunks (swizzled ds_read) ----
#pragma unroll
      for (int c = 0; c < 8; ++c)
#pragma unroll
        for (int kc = 0; kc < 2; ++kc) {
          const int d = c * 16 + l16;
          bf16x8 bv = *(const bf16x8*)(
              vsb + d * 128 + ((kc * 64 + quad * 16) ^ ((d & 7) << 4)));
          oacc[c] = __builtin_amdgcn_mfma_f32_16x16x32_bf16(pa[kc], bv, oacc[c], 0, 0, 0);
        }
    }

    // ---- epilogue: single l-reduce across 16-lane group, then store ----
#pragma unroll
    for (int r = 0; r < 4; ++r) {
#pragma unroll
      for (int msk = 1; msk < 16; msk <<= 1) lrun[r] += __shfl_xor(lrun[r], msk, 64);
      lrun[r] = 1.0f / lrun[r];
    }
#pragma unroll
    for (int c = 0; c < 8; ++c)
#pragma unroll
      for (int r = 0; r < 4; ++r) {
        int row = qbase + quad * 4 + r;
        o[((size_t)row * NH + h) * DH + c * 16 + l16] = (__bf16)(oacc[c][r] * lrun[r]);
      }
  }
}

// ---------------------------------------------------------------------------
extern "C" void kernel_launch(void* const* d_in, const int* in_sizes, int n_in,
                              void* d_out, int out_size, void* d_ws, size_t ws_size,
                              hipStream_t stream) {
  const float* x    = (const float*)d_in[0];
  const float* cosb = (const float*)d_in[1];
  const float* sinb = (const float*)d_in[2];
  // d_in[3] = mask (causal, reimplemented)
  const float* Wq  = (const float*)d_in[4];
  const float* bq  = (const float*)d_in[5];
  const float* Wk  = (const float*)d_in[6];
  const float* bk  = (const float*)d_in[7];
  const float* Wv  = (const float*)d_in[8];
  const float* bv  = (const float*)d_in[9];
  const float* Wo  = (const float*)d_in[10];
  const float* qnw = (const float*)d_in[11];
  const float* knw = (const float*)d_in[12];
  float* out = (float*)d_out;  // 4096x2048 fp32

  // ws (48 MB peak):
  char* ws = (char*)d_ws;
  __bf16* xb    = (__bf16*)(ws);                // 16 MB x bf16 (dies after v-GEMM)
  __bf16* Wqb   = (__bf16*)(ws + (16u << 20));  //  8 MB        (dies after q-GEMM)
  __bf16* Wkb   = (__bf16*)(ws + (24u << 20));  //  4 MB
  __bf16* Wvb   = (__bf16*)(ws + (28u << 20));  //  4 MB
  __bf16* kbuf  = (__bf16*)(ws + (32u << 20));  //  8 MB S x KVH x DH
  __bf16* vtbuf = (__bf16*)(ws + (40u << 20));  //  8 MB KVH x DH x S
  __bf16* Wob   = (__bf16*)(ws + (16u << 20));  //  8 MB (reuses Wqb slot)
  __bf16* ao    = (__bf16*)(ws);                // 16 MB attn out (reuses xb slot)
  // d_out doubles as scratch until the final GEMM:
  __bf16* qbuf = (__bf16*)d_out;                // 16 MB S x NH x DH

  dim3 blk(256);
  // fp32 -> bf16 converts
  f2b4<<<dim3(8192), blk, 0, stream>>>(x,  xb,  2097152);
  f2b4<<<dim3(4096), blk, 0, stream>>>(Wq, Wqb, 1048576);
  f2b4<<<dim3(2048), blk, 0, stream>>>(Wk, Wkb, 524288);
  f2b4<<<dim3(2048), blk, 0, stream>>>(Wv, Wvb, 524288);
  // q = x@Wq^T + bq  (4096x2048)
  gemm128<__bf16><<<dim3(16, 32), blk, 0, stream>>>(xb, Wqb, bq, qbuf, HID, HID, 1);
  // k = x@Wk^T + bk  (4096x1024)
  gemm128<__bf16><<<dim3(8, 32), blk, 0, stream>>>(xb, Wkb, bk, kbuf, KVH * DH, HID, 1);
  // v^T = Wv@x^T + bv[row]  (1024x4096)
  gemm128<__bf16><<<dim3(32, 8), blk, 0, stream>>>(Wvb, xb, bv, vtbuf, S_LEN, HID, 2);
  // rmsnorm + rope (in place; folds SCALE*LOG2E into q)
  rmsnorm_rope<<<dim3(S_LEN * (NH + KVH) / 4), blk, 0, stream>>>(
      qbuf, kbuf, cosb, sinb, qnw, knw);
  // Wo convert into dead Wqb slot (before attn so it overlaps the tail)
  f2b4<<<dim3(4096), blk, 0, stream>>>(Wo, Wob, 1048576);
  // attention -> ao (directly into dead xb slot; no memcpy)
  attn2<<<dim3(32, NH), blk, 0, stream>>>(qbuf, kbuf, vtbuf, ao);
  // out = ao @ Wo^T  (4096x2048, fp32 epilogue into full d_out)
  gemm128<float><<<dim3(16, 32), blk, 0, stream>>>(ao, Wob, nullptr, out, HID, HID, 0);
}

// Round 7
// 516.264 us; speedup vs baseline: 1.2395x; 1.0493x over previous
//
#include <hip/hip_runtime.h>
#include <hip/hip_bf16.h>
#include <stdint.h>

#define S_LEN 4096
#define HID 2048
#define NH 16
#define KVH 8
#define DH 128
#define EPS 1e-6f
#define SCALE 0.08838834764831845f  // 128^-0.5
#define LOG2E 1.4426950408889634f

#if __has_builtin(__builtin_amdgcn_exp2f)
#define EXP2(x) __builtin_amdgcn_exp2f(x)
#else
#define EXP2(x) exp2f(x)
#endif

typedef __bf16 bf16x8 __attribute__((ext_vector_type(8)));
typedef __bf16 bf16x4 __attribute__((ext_vector_type(4)));
typedef float f32x4 __attribute__((ext_vector_type(4)));

// Async global->LDS, 16B per lane. LDS dest must be wave-uniform base;
// lane i lands at dst + i*16B (m97/m104-verified semantics).
__device__ inline void gl_lds16(const __bf16* g, __bf16* l) {
  __builtin_amdgcn_global_load_lds(
      (const __attribute__((address_space(1))) void*)g,
      (__attribute__((address_space(3))) void*)l, 16, 0, 0);
}

// ---------------------------------------------------------------------------
// fp32 -> bf16 bulk convert (4 elems/thread).
// ---------------------------------------------------------------------------
__global__ __launch_bounds__(256) void f2b4(
    const float* __restrict__ in, __bf16* __restrict__ out, int n4) {
  int i = blockIdx.x * 256 + threadIdx.x;
  if (i < n4) {
    float4 v = ((const float4*)in)[i];
    bf16x4 o;
    o[0] = (__bf16)v.x; o[1] = (__bf16)v.y; o[2] = (__bf16)v.z; o[3] = (__bf16)v.w;
    ((bf16x4*)out)[i] = o;
  }
}

// ---------------------------------------------------------------------------
// NT GEMM v2: C(MxN) = A(MxK)@B(NxK)^T + bias. 128x128 tile, BK=32, 4 waves.
// R7: single-barrier double-buffered prefetch (R6-attn-verified pattern):
// stage tile kt+1's global_load_lds BEFORE computing tile kt; ONE barrier per
// K-step. The compiler's vmcnt(0)-before-barrier drains a prefetch that had a
// full compute phase to land. LDS 32KB (2 buffers).
// Split epilogue: cols >= nsplit go to C2 (ldc2) with bias2 — lets q & k
// GEMMs fuse into one dispatch (B = [Wq;Wk] contiguous, N=3072, 768 blocks).
// bias_mode: 0 none, 1 per-col, 2 per-row.
// ---------------------------------------------------------------------------
template <typename TC>
__global__ __launch_bounds__(256) void gemm128(
    const __bf16* __restrict__ A, const __bf16* __restrict__ B,
    const float* __restrict__ bias, TC* __restrict__ C,
    int N, int K, int bias_mode, int ldc,
    TC* __restrict__ C2, const float* __restrict__ bias2,
    int nsplit, int ldc2)
{
  __shared__ __attribute__((aligned(16))) __bf16 As[2][128 * 32];
  __shared__ __attribute__((aligned(16))) __bf16 Bs[2][128 * 32];
  const int wave = threadIdx.x >> 6, lane = threadIdx.x & 63;
  const int quad = lane >> 4, l16 = lane & 15;
  const int wm = wave >> 1, wn = wave & 1;
  const int m0 = blockIdx.y * 128, n0 = blockIdx.x * 128;
  const int srow = lane >> 2, scol = (lane & 3) * 8;  // staging lane map

  auto stage = [&](int buf, int k0) {
#pragma unroll
    for (int j = wave; j < 8; j += 4) {   // j wave-uniform
      gl_lds16(A + (size_t)(m0 + j * 16 + srow) * K + k0 + scol, &As[buf][j * 512]);
      gl_lds16(B + (size_t)(n0 + j * 16 + srow) * K + k0 + scol, &Bs[buf][j * 512]);
    }
  };

  f32x4 acc[4][4] = {};
  const int nk = K >> 5;
  stage(0, 0);  // prologue

  for (int kt = 0; kt < nk; ++kt) {
    const int cur = kt & 1;
    // Single barrier/K-step: own vmcnt(0) drain publishes buf[cur]; also
    // separates prev iter's buf[cur^1] reads from the restage below.
    __syncthreads();
    if (kt + 1 < nk) stage(cur ^ 1, (kt + 1) * 32);  // prefetch over compute

    bf16x8 af[4], bfr[4];
#pragma unroll
    for (int s = 0; s < 4; ++s) {
      af[s]  = *(const bf16x8*)(&As[cur][(wm * 64 + s * 16 + l16) * 32 + quad * 8]);
      bfr[s] = *(const bf16x8*)(&Bs[cur][(wn * 64 + s * 16 + l16) * 32 + quad * 8]);
    }
#pragma unroll
    for (int ms = 0; ms < 4; ++ms)
#pragma unroll
      for (int ns = 0; ns < 4; ++ns)
        acc[ms][ns] = __builtin_amdgcn_mfma_f32_16x16x32_bf16(
            af[ms], bfr[ns], acc[ms][ns], 0, 0, 0);
  }

#pragma unroll
  for (int ms = 0; ms < 4; ++ms)
#pragma unroll
    for (int ns = 0; ns < 4; ++ns)
#pragma unroll
      for (int r = 0; r < 4; ++r) {
        int row = m0 + wm * 64 + ms * 16 + quad * 4 + r;
        int col = n0 + wn * 64 + ns * 16 + l16;
        float v = acc[ms][ns][r];
        if (bias_mode == 1) v += (col < nsplit) ? bias[col] : bias2[col - nsplit];
        else if (bias_mode == 2) v += bias[row];
        if (col < nsplit) C[(size_t)row * ldc + col] = (TC)v;
        else              C2[(size_t)row * ldc2 + (col - nsplit)] = (TC)v;
      }
}

// ---------------------------------------------------------------------------
// Per-head RMSNorm (D=128) + RoPE, in-place on q,k (bf16). One wave/(s,head).
// SCALE*LOG2E folded into q output: attn scores land in log2 domain so
// softmax uses raw v_exp_f32 (2^x) with no per-element multiply.
// ---------------------------------------------------------------------------
__global__ __launch_bounds__(256) void rmsnorm_rope(
    __bf16* __restrict__ q, __bf16* __restrict__ k,
    const float* __restrict__ cosb, const float* __restrict__ sinb,
    const float* __restrict__ qw, const float* __restrict__ kw)
{
  const int wave = threadIdx.x >> 6;
  const int lane = threadIdx.x & 63;
  const int row = blockIdx.x * 4 + wave;
  const int s   = row / (NH + KVH);
  const int idx = row % (NH + KVH);

  __bf16* base;
  const float* w;
  float oscale;
  if (idx < NH) { base = q + ((size_t)s * NH + idx) * DH;         w = qw; oscale = SCALE * LOG2E; }
  else          { base = k + ((size_t)s * KVH + (idx - NH)) * DH; w = kw; oscale = 1.0f; }

  float x1 = (float)base[lane];
  float x2 = (float)base[lane + 64];
  float ss = x1 * x1 + x2 * x2;
#pragma unroll
  for (int m = 1; m < 64; m <<= 1) ss += __shfl_xor(ss, m, 64);
  float inv = rsqrtf(ss * (1.0f / 128.0f) + EPS);

  float xh1 = x1 * inv * w[lane];
  float xh2 = x2 * inv * w[lane + 64];
  const float* cs = cosb + (size_t)s * DH;
  const float* sn = sinb + (size_t)s * DH;
  base[lane]      = (__bf16)((xh1 * cs[lane]      - xh2 * sn[lane])      * oscale);
  base[lane + 64] = (__bf16)((xh2 * cs[lane + 64] + xh1 * sn[lane + 64]) * oscale);
}

// ---------------------------------------------------------------------------
// Flash attention v7 (R6-verified, 152us): causal, GQA reps=2. Grid (32, NH),
// block 256 (4 waves), triangle pairing {bx, 63-bx} -> uniform 65 k-tiles.
//  - double-buffered K/V, single barrier/tile, prefetch-over-compute.
//  - exp2-domain softmax (LOG2E pre-folded into q); T13 defer-max (THR=8).
//  - both-sides XOR swizzle on Ks/Vs (rule #21); diagonal-only mask.
//  - per-lane partial lrun, single epilogue reduce.
// ---------------------------------------------------------------------------
__global__ __launch_bounds__(256) void attn2(
    const __bf16* __restrict__ q,   // S x NH x DH  (pre-scaled by SCALE*LOG2E)
    const __bf16* __restrict__ k,   // S x KVH x DH
    const __bf16* __restrict__ vt,  // KVH x DH x S
    __bf16* __restrict__ o)         // S x NH x DH
{
  __shared__ __attribute__((aligned(16))) __bf16 Ks[2][64 * DH];  // 32KB swz
  __shared__ __attribute__((aligned(16))) __bf16 Vs[2][DH * 64];  // 32KB swz
  __shared__ __attribute__((aligned(16))) __bf16 pl[4][16 * 72];  // 9KB
  const int wave = threadIdx.x >> 6, lane = threadIdx.x & 63;
  const int quad = lane >> 4, l16 = lane & 15;
  const int h = blockIdx.y, kvh = h >> 1;

  const __bf16* kh = k + (size_t)kvh * DH;           // row s at + s*KVH*DH
  const __bf16* vh = vt + (size_t)kvh * DH * S_LEN;  // row d at + d*S_LEN

  // Loop-invariant staging lane offsets (4 K-issues + 4 V-issues per wave).
  int krow[4], kcol[4], vrow[4], vcol[4];
#pragma unroll
  for (int i = 0; i < 4; ++i) {
    int j = wave + i * 4;
    int r = j * 4 + (lane >> 4);
    int cbK = ((lane & 15) * 16) ^ ((r & 7) << 4);
    krow[i] = r; kcol[i] = cbK >> 1;
    int d = j * 8 + (lane >> 3);
    int cbV = ((lane & 7) * 16) ^ ((d & 7) << 4);
    vrow[i] = d; vcol[i] = cbV >> 1;
  }
  auto stage = [&](int buf, int k0) {
#pragma unroll
    for (int i = 0; i < 4; ++i)
      gl_lds16(kh + (size_t)(k0 + krow[i]) * (KVH * DH) + kcol[i],
               &Ks[buf][(wave + i * 4) * 512]);
#pragma unroll
    for (int i = 0; i < 4; ++i)
      gl_lds16(vh + (size_t)vrow[i] * S_LEN + k0 + vcol[i],
               &Vs[buf][(wave + i * 4) * 512]);
  };

  for (int phase = 0; phase < 2; ++phase) {
    const int qt = phase == 0 ? (int)blockIdx.x : 63 - (int)blockIdx.x;
    const int qbase = qt * 64 + wave * 16;

    bf16x8 qa[4];
    const __bf16* qrow = q + ((size_t)(qbase + l16) * NH + h) * DH + quad * 8;
#pragma unroll
    for (int c = 0; c < 4; ++c) qa[c] = *(const bf16x8*)(qrow + c * 32);

    f32x4 oacc[8] = {};
    float mrun[4], lrun[4];  // lrun = per-lane PARTIAL row-sum
#pragma unroll
    for (int r = 0; r < 4; ++r) { mrun[r] = -3.0e38f; lrun[r] = 0.0f; }

    __syncthreads();   // prev phase's last reads done before restage
    stage(0, 0);       // prologue

    for (int kt = 0; kt <= qt; ++kt) {
      const int cur = kt & 1;
      const int k0 = kt * 64;
      __syncthreads();
      if (kt < qt) stage(cur ^ 1, k0 + 64);  // prefetch flies over compute

      const char* ksb = (const char*)Ks[cur];
      const char* vsb = (const char*)Vs[cur];

      // ---- scores: 4 col-subtiles x 4 d-chunks (swizzled ds_read) ----
      f32x4 sc[4] = {};
#pragma unroll
      for (int tt = 0; tt < 4; ++tt) {
        const int row = tt * 16 + l16;
        const int swz = (row & 7) << 4;
#pragma unroll
        for (int c = 0; c < 4; ++c) {
          bf16x8 bk = *(const bf16x8*)(ksb + row * 256 + ((c * 64 + quad * 16) ^ swz));
          sc[tt] = __builtin_amdgcn_mfma_f32_16x16x32_bf16(qa[c], bk, sc[tt], 0, 0, 0);
        }
      }
      // ---- causal mask: only the diagonal tile ----
      if (kt == qt) {
#pragma unroll
        for (int tt = 0; tt < 4; ++tt)
#pragma unroll
          for (int r = 0; r < 4; ++r) {
            int col = k0 + tt * 16 + l16;
            int row = qbase + quad * 4 + r;
            if (col > row) sc[tt][r] = -3.0e38f;
          }
      }
      // ---- online softmax (log2 domain): T13 defer-max + deferred l-reduce --
      float pmax[4];
      bool defer = true;
#pragma unroll
      for (int r = 0; r < 4; ++r) {
        float mx = fmaxf(fmaxf(sc[0][r], sc[1][r]), fmaxf(sc[2][r], sc[3][r]));
        pmax[r] = mx;
        defer = defer && (mx - mrun[r] <= 8.0f);
      }
      if (__all(defer)) {
#pragma unroll
        for (int r = 0; r < 4; ++r) {
          float s0 = EXP2(sc[0][r] - mrun[r]);
          float s1 = EXP2(sc[1][r] - mrun[r]);
          float s2 = EXP2(sc[2][r] - mrun[r]);
          float s3 = EXP2(sc[3][r] - mrun[r]);
          sc[0][r] = s0; sc[1][r] = s1; sc[2][r] = s2; sc[3][r] = s3;
          lrun[r] += (s0 + s1) + (s2 + s3);   // per-lane partial
        }
      } else {
#pragma unroll
        for (int r = 0; r < 4; ++r) {
          float mx = pmax[r];
#pragma unroll
          for (int msk = 1; msk < 16; msk <<= 1) mx = fmaxf(mx, __shfl_xor(mx, msk, 64));
          float mnew = fmaxf(mrun[r], mx);     // uniform within 16-lane group
          float sum = 0.0f;
#pragma unroll
          for (int tt = 0; tt < 4; ++tt) {
            float p = EXP2(sc[tt][r] - mnew);
            sc[tt][r] = p;
            sum += p;
          }
          float alpha = EXP2(mrun[r] - mnew);  // uniform -> partial-scale ok
          lrun[r] = lrun[r] * alpha + sum;
          mrun[r] = mnew;
#pragma unroll
          for (int c = 0; c < 8; ++c) oacc[c][r] *= alpha;
        }
      }
      // ---- P: C-layout -> A-layout via per-wave slab (stride 72) ----
#pragma unroll
      for (int tt = 0; tt < 4; ++tt)
#pragma unroll
        for (int r = 0; r < 4; ++r)
          pl[wave][(quad * 4 + r) * 72 + tt * 16 + l16] = (__bf16)sc[tt][r];
      bf16x8 pa[2];
#pragma unroll
      for (int kc = 0; kc < 2; ++kc)
        pa[kc] = *(const bf16x8*)(pl[wave] + l16 * 72 + kc * 32 + quad * 8);
      // ---- PV: 8 d-chunks x 2 k-chunks (swizzled ds_read) ----
#pragma unroll
      for (int c = 0; c < 8; ++c)
#pragma unroll
        for (int kc = 0; kc < 2; ++kc) {
          const int d = c * 16 + l16;
          bf16x8 bv = *(const bf16x8*)(
              vsb + d * 128 + ((kc * 64 + quad * 16) ^ ((d & 7) << 4)));
          oacc[c] = __builtin_amdgcn_mfma_f32_16x16x32_bf16(pa[kc], bv, oacc[c], 0, 0, 0);
        }
    }

    // ---- epilogue: single l-reduce across 16-lane group, then store ----
#pragma unroll
    for (int r = 0; r < 4; ++r) {
#pragma unroll
      for (int msk = 1; msk < 16; msk <<= 1) lrun[r] += __shfl_xor(lrun[r], msk, 64);
      lrun[r] = 1.0f / lrun[r];
    }
#pragma unroll
    for (int c = 0; c < 8; ++c)
#pragma unroll
      for (int r = 0; r < 4; ++r) {
        int row = qbase + quad * 4 + r;
        o[((size_t)row * NH + h) * DH + c * 16 + l16] = (__bf16)(oacc[c][r] * lrun[r]);
      }
  }
}

// ---------------------------------------------------------------------------
extern "C" void kernel_launch(void* const* d_in, const int* in_sizes, int n_in,
                              void* d_out, int out_size, void* d_ws, size_t ws_size,
                              hipStream_t stream) {
  const float* x    = (const float*)d_in[0];
  const float* cosb = (const float*)d_in[1];
  const float* sinb = (const float*)d_in[2];
  // d_in[3] = mask (causal, reimplemented)
  const float* Wq  = (const float*)d_in[4];
  const float* bq  = (const float*)d_in[5];
  const float* Wk  = (const float*)d_in[6];
  const float* bk  = (const float*)d_in[7];
  const float* Wv  = (const float*)d_in[8];
  const float* bv  = (const float*)d_in[9];
  const float* Wo  = (const float*)d_in[10];
  const float* qnw = (const float*)d_in[11];
  const float* knw = (const float*)d_in[12];
  float* out = (float*)d_out;  // 4096x2048 fp32

  // ws (48 MB peak):
  char* ws = (char*)d_ws;
  __bf16* xb    = (__bf16*)(ws);                // 16 MB x bf16 (dies after v-GEMM)
  __bf16* Wqb   = (__bf16*)(ws + (16u << 20));  //  8 MB  [Wq;Wk] contiguous ->
  __bf16* Wkb   = (__bf16*)(ws + (24u << 20));  //  4 MB  single 3072-row B
  __bf16* Wvb   = (__bf16*)(ws + (28u << 20));  //  4 MB
  __bf16* kbuf  = (__bf16*)(ws + (32u << 20));  //  8 MB S x KVH x DH
  __bf16* vtbuf = (__bf16*)(ws + (40u << 20));  //  8 MB KVH x DH x S
  __bf16* Wob   = (__bf16*)(ws + (16u << 20));  //  8 MB (reuses Wqb slot)
  __bf16* ao    = (__bf16*)(ws);                // 16 MB attn out (reuses xb slot)
  // d_out doubles as scratch until the final GEMM:
  __bf16* qbuf = (__bf16*)d_out;                // 16 MB S x NH x DH

  dim3 blk(256);
  // fp32 -> bf16 converts
  f2b4<<<dim3(8192), blk, 0, stream>>>(x,  xb,  2097152);
  f2b4<<<dim3(4096), blk, 0, stream>>>(Wq, Wqb, 1048576);
  f2b4<<<dim3(2048), blk, 0, stream>>>(Wk, Wkb, 524288);
  f2b4<<<dim3(2048), blk, 0, stream>>>(Wv, Wvb, 524288);
  // fused q|k GEMM: x @ [Wq;Wk]^T, N=3072, split epilogue -> qbuf / kbuf
  // (768 blocks = 3/CU vs 512+256 with a 1-block/CU k-GEMM)
  gemm128<__bf16><<<dim3(24, 32), blk, 0, stream>>>(
      xb, Wqb, bq, qbuf, 3072, HID, 1, HID, kbuf, bk, HID, KVH * DH);
  // v^T = Wv@x^T + bv[row]  (1024x4096)
  gemm128<__bf16><<<dim3(32, 8), blk, 0, stream>>>(
      Wvb, xb, bv, vtbuf, S_LEN, HID, 2, S_LEN, nullptr, nullptr, S_LEN, 0);
  // rmsnorm + rope (in place; folds SCALE*LOG2E into q)
  rmsnorm_rope<<<dim3(S_LEN * (NH + KVH) / 4), blk, 0, stream>>>(
      qbuf, kbuf, cosb, sinb, qnw, knw);
  // Wo convert into dead Wqb slot (before attn so it overlaps the tail)
  f2b4<<<dim3(4096), blk, 0, stream>>>(Wo, Wob, 1048576);
  // attention -> ao (directly into dead xb slot; no memcpy)
  attn2<<<dim3(32, NH), blk, 0, stream>>>(qbuf, kbuf, vtbuf, ao);
  // out = ao @ Wo^T  (4096x2048, fp32 epilogue into full d_out)
  gemm128<float><<<dim3(16, 32), blk, 0, stream>>>(
      ao, Wob, nullptr, out, HID, HID, 0, HID, nullptr, nullptr, HID, 0);
}

// Round 8
// 494.081 us; speedup vs baseline: 1.2952x; 1.0449x over previous
//
#include <hip/hip_runtime.h>
#include <hip/hip_bf16.h>
#include <stdint.h>

#define S_LEN 4096
#define HID 2048
#define NH 16
#define KVH 8
#define DH 128
#define EPS 1e-6f
#define SCALE 0.08838834764831845f  // 128^-0.5
#define LOG2E 1.4426950408889634f

#if __has_builtin(__builtin_amdgcn_exp2f)
#define EXP2(x) __builtin_amdgcn_exp2f(x)
#else
#define EXP2(x) exp2f(x)
#endif

typedef __bf16 bf16x8 __attribute__((ext_vector_type(8)));
typedef __bf16 bf16x4 __attribute__((ext_vector_type(4)));
typedef float f32x4 __attribute__((ext_vector_type(4)));

// Async global->LDS, 16B per lane. LDS dest must be wave-uniform base;
// lane i lands at dst + i*16B (m97/m104-verified semantics).
__device__ inline void gl_lds16(const __bf16* g, __bf16* l) {
  __builtin_amdgcn_global_load_lds(
      (const __attribute__((address_space(1))) void*)g,
      (__attribute__((address_space(3))) void*)l, 16, 0, 0);
}

// ---------------------------------------------------------------------------
// fp32 -> bf16 bulk convert (4 elems/thread).
// ---------------------------------------------------------------------------
__global__ __launch_bounds__(256) void f2b4(
    const float* __restrict__ in, __bf16* __restrict__ out, int n4) {
  int i = blockIdx.x * 256 + threadIdx.x;
  if (i < n4) {
    float4 v = ((const float4*)in)[i];
    bf16x4 o;
    o[0] = (__bf16)v.x; o[1] = (__bf16)v.y; o[2] = (__bf16)v.z; o[3] = (__bf16)v.w;
    ((bf16x4*)out)[i] = o;
  }
}

// ---------------------------------------------------------------------------
// NT GEMM (R7-verified dbuf): C(MxN) = A(MxK)@B(NxK)^T + bias. 128x128 tile,
// BK=32, 4 waves, single-barrier prefetch-over-compute, LDS 32KB.
// bias_mode: 0 none, 1 per-col, 2 per-row.
// ---------------------------------------------------------------------------
template <typename TC>
__global__ __launch_bounds__(256) void gemm128(
    const __bf16* __restrict__ A, const __bf16* __restrict__ B,
    const float* __restrict__ bias, TC* __restrict__ C,
    int N, int K, int bias_mode)
{
  __shared__ __attribute__((aligned(16))) __bf16 As[2][128 * 32];
  __shared__ __attribute__((aligned(16))) __bf16 Bs[2][128 * 32];
  const int wave = threadIdx.x >> 6, lane = threadIdx.x & 63;
  const int quad = lane >> 4, l16 = lane & 15;
  const int wm = wave >> 1, wn = wave & 1;
  const int m0 = blockIdx.y * 128, n0 = blockIdx.x * 128;
  const int srow = lane >> 2, scol = (lane & 3) * 8;  // staging lane map

  auto stage = [&](int buf, int k0) {
#pragma unroll
    for (int j = wave; j < 8; j += 4) {   // j wave-uniform
      gl_lds16(A + (size_t)(m0 + j * 16 + srow) * K + k0 + scol, &As[buf][j * 512]);
      gl_lds16(B + (size_t)(n0 + j * 16 + srow) * K + k0 + scol, &Bs[buf][j * 512]);
    }
  };

  f32x4 acc[4][4] = {};
  const int nk = K >> 5;
  stage(0, 0);  // prologue

  for (int kt = 0; kt < nk; ++kt) {
    const int cur = kt & 1;
    __syncthreads();   // vmcnt(0) drain publishes buf[cur]; guards restage
    if (kt + 1 < nk) stage(cur ^ 1, (kt + 1) * 32);  // prefetch over compute

    bf16x8 af[4], bfr[4];
#pragma unroll
    for (int s = 0; s < 4; ++s) {
      af[s]  = *(const bf16x8*)(&As[cur][(wm * 64 + s * 16 + l16) * 32 + quad * 8]);
      bfr[s] = *(const bf16x8*)(&Bs[cur][(wn * 64 + s * 16 + l16) * 32 + quad * 8]);
    }
#pragma unroll
    for (int ms = 0; ms < 4; ++ms)
#pragma unroll
      for (int ns = 0; ns < 4; ++ns)
        acc[ms][ns] = __builtin_amdgcn_mfma_f32_16x16x32_bf16(
            af[ms], bfr[ns], acc[ms][ns], 0, 0, 0);
  }

#pragma unroll
  for (int ms = 0; ms < 4; ++ms)
#pragma unroll
    for (int ns = 0; ns < 4; ++ns)
#pragma unroll
      for (int r = 0; r < 4; ++r) {
        int row = m0 + wm * 64 + ms * 16 + quad * 4 + r;
        int col = n0 + wn * 64 + ns * 16 + l16;
        float v = acc[ms][ns][r];
        if (bias_mode == 1) v += bias[col];
        else if (bias_mode == 2) v += bias[row];
        C[(size_t)row * N + col] = (TC)v;
      }
}

// ---------------------------------------------------------------------------
// R8: fused QKV GEMM. A = x (4096x2048), B = [Wq;Wk;Wv] (4096x2048,
// contiguous in ws). Grid (32,32) = 1024 blocks = 4/CU (v-GEMM alone was
// 256 blocks = 1/CU, latency-exposed). Same dbuf main loop as gemm128.
// Region by col-block (128-col blocks never straddle): bx<16 -> q (row-major
// + bq), 16<=bx<24 -> k (row-major + bk), bx>=24 -> v written TRANSPOSED
// directly from registers: for fixed (lane,ns) the r=0..3 acc values are
// consecutive s -> one bf16x4 (8B) store at vt[vr*S_LEN + s0]. Each 64B vt
// line is fully covered by the block's stores (s spans m0..m0+127), so L2
// write-combines the scatter; volume unchanged (8MB).
// ---------------------------------------------------------------------------
__global__ __launch_bounds__(256) void gemm_qkv(
    const __bf16* __restrict__ A,   // x: 4096 x 2048
    const __bf16* __restrict__ B,   // [Wq;Wk;Wv]: 4096 x 2048
    const float* __restrict__ bq, const float* __restrict__ bk,
    const float* __restrict__ bv,
    __bf16* __restrict__ qo,        // 4096 x 2048 (S x NH x DH)
    __bf16* __restrict__ ko,        // 4096 x 1024 (S x KVH x DH)
    __bf16* __restrict__ vto)       // 1024 x 4096 (KVH x DH x S)
{
  __shared__ __attribute__((aligned(16))) __bf16 As[2][128 * 32];
  __shared__ __attribute__((aligned(16))) __bf16 Bs[2][128 * 32];
  const int wave = threadIdx.x >> 6, lane = threadIdx.x & 63;
  const int quad = lane >> 4, l16 = lane & 15;
  const int wm = wave >> 1, wn = wave & 1;
  const int m0 = blockIdx.y * 128, n0 = blockIdx.x * 128;
  const int srow = lane >> 2, scol = (lane & 3) * 8;
  const int K = HID;

  auto stage = [&](int buf, int k0) {
#pragma unroll
    for (int j = wave; j < 8; j += 4) {
      gl_lds16(A + (size_t)(m0 + j * 16 + srow) * K + k0 + scol, &As[buf][j * 512]);
      gl_lds16(B + (size_t)(n0 + j * 16 + srow) * K + k0 + scol, &Bs[buf][j * 512]);
    }
  };

  f32x4 acc[4][4] = {};
  const int nk = K >> 5;   // 64 K-steps
  stage(0, 0);

  for (int kt = 0; kt < nk; ++kt) {
    const int cur = kt & 1;
    __syncthreads();
    if (kt + 1 < nk) stage(cur ^ 1, (kt + 1) * 32);

    bf16x8 af[4], bfr[4];
#pragma unroll
    for (int s = 0; s < 4; ++s) {
      af[s]  = *(const bf16x8*)(&As[cur][(wm * 64 + s * 16 + l16) * 32 + quad * 8]);
      bfr[s] = *(const bf16x8*)(&Bs[cur][(wn * 64 + s * 16 + l16) * 32 + quad * 8]);
    }
#pragma unroll
    for (int ms = 0; ms < 4; ++ms)
#pragma unroll
      for (int ns = 0; ns < 4; ++ns)
        acc[ms][ns] = __builtin_amdgcn_mfma_f32_16x16x32_bf16(
            af[ms], bfr[ns], acc[ms][ns], 0, 0, 0);
  }

  if (blockIdx.x < 24) {
    // ---- q / k region: coalesced row-major store ----
#pragma unroll
    for (int ms = 0; ms < 4; ++ms)
#pragma unroll
      for (int ns = 0; ns < 4; ++ns)
#pragma unroll
        for (int r = 0; r < 4; ++r) {
          int row = m0 + wm * 64 + ms * 16 + quad * 4 + r;
          int col = n0 + wn * 64 + ns * 16 + l16;
          float v = acc[ms][ns][r];
          if (col < 2048) { v += bq[col];        qo[(size_t)row * HID + col] = (__bf16)v; }
          else            { v += bk[col - 2048]; ko[(size_t)row * (KVH * DH) + (col - 2048)] = (__bf16)v; }
        }
  } else {
    // ---- v region: transposed register scatter (bf16x4 = 4 consecutive s) --
#pragma unroll
    for (int ms = 0; ms < 4; ++ms)
#pragma unroll
      for (int ns = 0; ns < 4; ++ns) {
        int vr = n0 - 3072 + wn * 64 + ns * 16 + l16;   // 0..1023 = kvh*DH+d
        int s0 = m0 + wm * 64 + ms * 16 + quad * 4;
        float b = bv[vr];
        bf16x4 p;
#pragma unroll
        for (int r = 0; r < 4; ++r) p[r] = (__bf16)(acc[ms][ns][r] + b);
        *(bf16x4*)(vto + (size_t)vr * S_LEN + s0) = p;
      }
  }
}

// ---------------------------------------------------------------------------
// Per-head RMSNorm (D=128) + RoPE, in-place on q,k (bf16). One wave/(s,head).
// SCALE*LOG2E folded into q output: attn scores land in log2 domain so
// softmax uses raw v_exp_f32 (2^x) with no per-element multiply.
// ---------------------------------------------------------------------------
__global__ __launch_bounds__(256) void rmsnorm_rope(
    __bf16* __restrict__ q, __bf16* __restrict__ k,
    const float* __restrict__ cosb, const float* __restrict__ sinb,
    const float* __restrict__ qw, const float* __restrict__ kw)
{
  const int wave = threadIdx.x >> 6;
  const int lane = threadIdx.x & 63;
  const int row = blockIdx.x * 4 + wave;
  const int s   = row / (NH + KVH);
  const int idx = row % (NH + KVH);

  __bf16* base;
  const float* w;
  float oscale;
  if (idx < NH) { base = q + ((size_t)s * NH + idx) * DH;         w = qw; oscale = SCALE * LOG2E; }
  else          { base = k + ((size_t)s * KVH + (idx - NH)) * DH; w = kw; oscale = 1.0f; }

  float x1 = (float)base[lane];
  float x2 = (float)base[lane + 64];
  float ss = x1 * x1 + x2 * x2;
#pragma unroll
  for (int m = 1; m < 64; m <<= 1) ss += __shfl_xor(ss, m, 64);
  float inv = rsqrtf(ss * (1.0f / 128.0f) + EPS);

  float xh1 = x1 * inv * w[lane];
  float xh2 = x2 * inv * w[lane + 64];
  const float* cs = cosb + (size_t)s * DH;
  const float* sn = sinb + (size_t)s * DH;
  base[lane]      = (__bf16)((xh1 * cs[lane]      - xh2 * sn[lane])      * oscale);
  base[lane + 64] = (__bf16)((xh2 * cs[lane + 64] + xh1 * sn[lane + 64]) * oscale);
}

// ---------------------------------------------------------------------------
// Flash attention v7 (R6-verified, 152us): causal, GQA reps=2. Grid (32, NH),
// block 256 (4 waves), triangle pairing {bx, 63-bx} -> uniform 65 k-tiles.
//  - double-buffered K/V, single barrier/tile, prefetch-over-compute.
//  - exp2-domain softmax (LOG2E pre-folded into q); T13 defer-max (THR=8).
//  - both-sides XOR swizzle on Ks/Vs (rule #21); diagonal-only mask.
//  - per-lane partial lrun, single epilogue reduce.
// ---------------------------------------------------------------------------
__global__ __launch_bounds__(256) void attn2(
    const __bf16* __restrict__ q,   // S x NH x DH  (pre-scaled by SCALE*LOG2E)
    const __bf16* __restrict__ k,   // S x KVH x DH
    const __bf16* __restrict__ vt,  // KVH x DH x S
    __bf16* __restrict__ o)         // S x NH x DH
{
  __shared__ __attribute__((aligned(16))) __bf16 Ks[2][64 * DH];  // 32KB swz
  __shared__ __attribute__((aligned(16))) __bf16 Vs[2][DH * 64];  // 32KB swz
  __shared__ __attribute__((aligned(16))) __bf16 pl[4][16 * 72];  // 9KB
  const int wave = threadIdx.x >> 6, lane = threadIdx.x & 63;
  const int quad = lane >> 4, l16 = lane & 15;
  const int h = blockIdx.y, kvh = h >> 1;

  const __bf16* kh = k + (size_t)kvh * DH;           // row s at + s*KVH*DH
  const __bf16* vh = vt + (size_t)kvh * DH * S_LEN;  // row d at + d*S_LEN

  // Loop-invariant staging lane offsets (4 K-issues + 4 V-issues per wave).
  int krow[4], kcol[4], vrow[4], vcol[4];
#pragma unroll
  for (int i = 0; i < 4; ++i) {
    int j = wave + i * 4;
    int r = j * 4 + (lane >> 4);
    int cbK = ((lane & 15) * 16) ^ ((r & 7) << 4);
    krow[i] = r; kcol[i] = cbK >> 1;
    int d = j * 8 + (lane >> 3);
    int cbV = ((lane & 7) * 16) ^ ((d & 7) << 4);
    vrow[i] = d; vcol[i] = cbV >> 1;
  }
  auto stage = [&](int buf, int k0) {
#pragma unroll
    for (int i = 0; i < 4; ++i)
      gl_lds16(kh + (size_t)(k0 + krow[i]) * (KVH * DH) + kcol[i],
               &Ks[buf][(wave + i * 4) * 512]);
#pragma unroll
    for (int i = 0; i < 4; ++i)
      gl_lds16(vh + (size_t)vrow[i] * S_LEN + k0 + vcol[i],
               &Vs[buf][(wave + i * 4) * 512]);
  };

  for (int phase = 0; phase < 2; ++phase) {
    const int qt = phase == 0 ? (int)blockIdx.x : 63 - (int)blockIdx.x;
    const int qbase = qt * 64 + wave * 16;

    bf16x8 qa[4];
    const __bf16* qrow = q + ((size_t)(qbase + l16) * NH + h) * DH + quad * 8;
#pragma unroll
    for (int c = 0; c < 4; ++c) qa[c] = *(const bf16x8*)(qrow + c * 32);

    f32x4 oacc[8] = {};
    float mrun[4], lrun[4];  // lrun = per-lane PARTIAL row-sum
#pragma unroll
    for (int r = 0; r < 4; ++r) { mrun[r] = -3.0e38f; lrun[r] = 0.0f; }

    __syncthreads();   // prev phase's last reads done before restage
    stage(0, 0);       // prologue

    for (int kt = 0; kt <= qt; ++kt) {
      const int cur = kt & 1;
      const int k0 = kt * 64;
      __syncthreads();
      if (kt < qt) stage(cur ^ 1, k0 + 64);  // prefetch flies over compute

      const char* ksb = (const char*)Ks[cur];
      const char* vsb = (const char*)Vs[cur];

      // ---- scores: 4 col-subtiles x 4 d-chunks (swizzled ds_read) ----
      f32x4 sc[4] = {};
#pragma unroll
      for (int tt = 0; tt < 4; ++tt) {
        const int row = tt * 16 + l16;
        const int swz = (row & 7) << 4;
#pragma unroll
        for (int c = 0; c < 4; ++c) {
          bf16x8 bk = *(const bf16x8*)(ksb + row * 256 + ((c * 64 + quad * 16) ^ swz));
          sc[tt] = __builtin_amdgcn_mfma_f32_16x16x32_bf16(qa[c], bk, sc[tt], 0, 0, 0);
        }
      }
      // ---- causal mask: only the diagonal tile ----
      if (kt == qt) {
#pragma unroll
        for (int tt = 0; tt < 4; ++tt)
#pragma unroll
          for (int r = 0; r < 4; ++r) {
            int col = k0 + tt * 16 + l16;
            int row = qbase + quad * 4 + r;
            if (col > row) sc[tt][r] = -3.0e38f;
          }
      }
      // ---- online softmax (log2 domain): T13 defer-max + deferred l-reduce --
      float pmax[4];
      bool defer = true;
#pragma unroll
      for (int r = 0; r < 4; ++r) {
        float mx = fmaxf(fmaxf(sc[0][r], sc[1][r]), fmaxf(sc[2][r], sc[3][r]));
        pmax[r] = mx;
        defer = defer && (mx - mrun[r] <= 8.0f);
      }
      if (__all(defer)) {
#pragma unroll
        for (int r = 0; r < 4; ++r) {
          float s0 = EXP2(sc[0][r] - mrun[r]);
          float s1 = EXP2(sc[1][r] - mrun[r]);
          float s2 = EXP2(sc[2][r] - mrun[r]);
          float s3 = EXP2(sc[3][r] - mrun[r]);
          sc[0][r] = s0; sc[1][r] = s1; sc[2][r] = s2; sc[3][r] = s3;
          lrun[r] += (s0 + s1) + (s2 + s3);   // per-lane partial
        }
      } else {
#pragma unroll
        for (int r = 0; r < 4; ++r) {
          float mx = pmax[r];
#pragma unroll
          for (int msk = 1; msk < 16; msk <<= 1) mx = fmaxf(mx, __shfl_xor(mx, msk, 64));
          float mnew = fmaxf(mrun[r], mx);     // uniform within 16-lane group
          float sum = 0.0f;
#pragma unroll
          for (int tt = 0; tt < 4; ++tt) {
            float p = EXP2(sc[tt][r] - mnew);
            sc[tt][r] = p;
            sum += p;
          }
          float alpha = EXP2(mrun[r] - mnew);  // uniform -> partial-scale ok
          lrun[r] = lrun[r] * alpha + sum;
          mrun[r] = mnew;
#pragma unroll
          for (int c = 0; c < 8; ++c) oacc[c][r] *= alpha;
        }
      }
      // ---- P: C-layout -> A-layout via per-wave slab (stride 72) ----
#pragma unroll
      for (int tt = 0; tt < 4; ++tt)
#pragma unroll
        for (int r = 0; r < 4; ++r)
          pl[wave][(quad * 4 + r) * 72 + tt * 16 + l16] = (__bf16)sc[tt][r];
      bf16x8 pa[2];
#pragma unroll
      for (int kc = 0; kc < 2; ++kc)
        pa[kc] = *(const bf16x8*)(pl[wave] + l16 * 72 + kc * 32 + quad * 8);
      // ---- PV: 8 d-chunks x 2 k-chunks (swizzled ds_read) ----
#pragma unroll
      for (int c = 0; c < 8; ++c)
#pragma unroll
        for (int kc = 0; kc < 2; ++kc) {
          const int d = c * 16 + l16;
          bf16x8 bv = *(const bf16x8*)(
              vsb + d * 128 + ((kc * 64 + quad * 16) ^ ((d & 7) << 4)));
          oacc[c] = __builtin_amdgcn_mfma_f32_16x16x32_bf16(pa[kc], bv, oacc[c], 0, 0, 0);
        }
    }

    // ---- epilogue: single l-reduce across 16-lane group, then store ----
#pragma unroll
    for (int r = 0; r < 4; ++r) {
#pragma unroll
      for (int msk = 1; msk < 16; msk <<= 1) lrun[r] += __shfl_xor(lrun[r], msk, 64);
      lrun[r] = 1.0f / lrun[r];
    }
#pragma unroll
    for (int c = 0; c < 8; ++c)
#pragma unroll
      for (int r = 0; r < 4; ++r) {
        int row = qbase + quad * 4 + r;
        o[((size_t)row * NH + h) * DH + c * 16 + l16] = (__bf16)(oacc[c][r] * lrun[r]);
      }
  }
}

// ---------------------------------------------------------------------------
extern "C" void kernel_launch(void* const* d_in, const int* in_sizes, int n_in,
                              void* d_out, int out_size, void* d_ws, size_t ws_size,
                              hipStream_t stream) {
  const float* x    = (const float*)d_in[0];
  const float* cosb = (const float*)d_in[1];
  const float* sinb = (const float*)d_in[2];
  // d_in[3] = mask (causal, reimplemented)
  const float* Wq  = (const float*)d_in[4];
  const float* bq  = (const float*)d_in[5];
  const float* Wk  = (const float*)d_in[6];
  const float* bk  = (const float*)d_in[7];
  const float* Wv  = (const float*)d_in[8];
  const float* bv  = (const float*)d_in[9];
  const float* Wo  = (const float*)d_in[10];
  const float* qnw = (const float*)d_in[11];
  const float* knw = (const float*)d_in[12];
  float* out = (float*)d_out;  // 4096x2048 fp32

  // ws (48 MB peak):
  char* ws = (char*)d_ws;
  __bf16* xb    = (__bf16*)(ws);                // 16 MB x bf16 (dies after qkv-GEMM)
  __bf16* Wqb   = (__bf16*)(ws + (16u << 20));  //  8 MB  [Wq;Wk;Wv] contiguous
  __bf16* Wkb   = (__bf16*)(ws + (24u << 20));  //  4 MB  16MB B for fused GEMM
  __bf16* Wvb   = (__bf16*)(ws + (28u << 20));  //  4 MB
  __bf16* kbuf  = (__bf16*)(ws + (32u << 20));  //  8 MB S x KVH x DH
  __bf16* vtbuf = (__bf16*)(ws + (40u << 20));  //  8 MB KVH x DH x S
  __bf16* Wob   = (__bf16*)(ws + (16u << 20));  //  8 MB (reuses Wqb slot)
  __bf16* ao    = (__bf16*)(ws);                // 16 MB attn out (reuses xb slot)
  // d_out doubles as scratch until the final GEMM:
  __bf16* qbuf = (__bf16*)d_out;                // 16 MB S x NH x DH

  dim3 blk(256);
  // fp32 -> bf16 converts
  f2b4<<<dim3(8192), blk, 0, stream>>>(x,  xb,  2097152);
  f2b4<<<dim3(4096), blk, 0, stream>>>(Wq, Wqb, 1048576);
  f2b4<<<dim3(2048), blk, 0, stream>>>(Wk, Wkb, 524288);
  f2b4<<<dim3(2048), blk, 0, stream>>>(Wv, Wvb, 524288);
  // fused q|k|v GEMM: x @ [Wq;Wk;Wv]^T, N=4096, 1024 blocks = 4/CU.
  // q,k row-major; v written transposed (vt) straight from registers.
  gemm_qkv<<<dim3(32, 32), blk, 0, stream>>>(
      xb, Wqb, bq, bk, bv, qbuf, kbuf, vtbuf);
  // rmsnorm + rope (in place; folds SCALE*LOG2E into q)
  rmsnorm_rope<<<dim3(S_LEN * (NH + KVH) / 4), blk, 0, stream>>>(
      qbuf, kbuf, cosb, sinb, qnw, knw);
  // Wo convert into dead Wqb slot (before attn so it overlaps the tail)
  f2b4<<<dim3(4096), blk, 0, stream>>>(Wo, Wob, 1048576);
  // attention -> ao (directly into dead xb slot)
  attn2<<<dim3(32, NH), blk, 0, stream>>>(qbuf, kbuf, vtbuf, ao);
  // out = ao @ Wo^T  (4096x2048, fp32 epilogue into full d_out)
  gemm128<float><<<dim3(16, 32), blk, 0, stream>>>(ao, Wob, nullptr, out, HID, HID, 0);
}

// Round 9
// 475.760 us; speedup vs baseline: 1.3450x; 1.0385x over previous
//
#include <hip/hip_runtime.h>
#include <hip/hip_bf16.h>
#include <stdint.h>

#define S_LEN 4096
#define HID 2048
#define NH 16
#define KVH 8
#define DH 128
#define EPS 1e-6f
#define SCALE 0.08838834764831845f  // 128^-0.5
#define LOG2E 1.4426950408889634f

#if __has_builtin(__builtin_amdgcn_exp2f)
#define EXP2(x) __builtin_amdgcn_exp2f(x)
#else
#define EXP2(x) exp2f(x)
#endif

typedef __bf16 bf16x8 __attribute__((ext_vector_type(8)));
typedef __bf16 bf16x4 __attribute__((ext_vector_type(4)));
typedef float f32x4 __attribute__((ext_vector_type(4)));

// Async global->LDS, 16B per lane. LDS dest must be wave-uniform base;
// lane i lands at dst + i*16B (m97/m104-verified semantics).
__device__ inline void gl_lds16(const __bf16* g, __bf16* l) {
  __builtin_amdgcn_global_load_lds(
      (const __attribute__((address_space(1))) void*)g,
      (__attribute__((address_space(3))) void*)l, 16, 0, 0);
}

// ---------------------------------------------------------------------------
// fp32 -> bf16 bulk convert (4 elems/thread).
// ---------------------------------------------------------------------------
__global__ __launch_bounds__(256) void f2b4(
    const float* __restrict__ in, __bf16* __restrict__ out, int n4) {
  int i = blockIdx.x * 256 + threadIdx.x;
  if (i < n4) {
    float4 v = ((const float4*)in)[i];
    bf16x4 o;
    o[0] = (__bf16)v.x; o[1] = (__bf16)v.y; o[2] = (__bf16)v.z; o[3] = (__bf16)v.w;
    ((bf16x4*)out)[i] = o;
  }
}

// ===========================================================================
// R9 GEMM main-loop: triple-buffered LDS, 2-tile prefetch lead, counted
// vmcnt (T4: never drain to 0 in the main loop). Per tile t:
//   s_waitcnt vmcnt(4)  -> my 4 loads of stage t landed; stage t+1 (4 loads)
//                          stays IN FLIGHT across the barrier
//   s_barrier           -> raw barrier (NOT __syncthreads: that emits
//                          vmcnt(0) and re-exposes the full load latency)
//   issue stage t+2     -> into buf[(t+2)%3]; tile t-1's reads of that
//                          buffer executed before barrier(t) -> race-free
//   ds_read buf[t%3] + 16 MFMA (compiler inserts lgkmcnt for ds->MFMA)
// Last tile: vmcnt(0) (nothing newer to keep in flight).
// ===========================================================================

// ---------------------------------------------------------------------------
// NT GEMM: C(MxN) = A(MxK)@B(NxK)^T + bias. 128x128 tile, BK=32, 4 waves.
// bias_mode: 0 none, 1 per-col, 2 per-row.
// ---------------------------------------------------------------------------
template <typename TC>
__global__ __launch_bounds__(256) void gemm128(
    const __bf16* __restrict__ A, const __bf16* __restrict__ B,
    const float* __restrict__ bias, TC* __restrict__ C,
    int N, int K, int bias_mode)
{
  __shared__ __attribute__((aligned(16))) __bf16 As[3][128 * 32];  // 24KB
  __shared__ __attribute__((aligned(16))) __bf16 Bs[3][128 * 32];  // 24KB
  const int wave = threadIdx.x >> 6, lane = threadIdx.x & 63;
  const int quad = lane >> 4, l16 = lane & 15;
  const int wm = wave >> 1, wn = wave & 1;
  const int m0 = blockIdx.y * 128, n0 = blockIdx.x * 128;
  const int srow = lane >> 2, scol = (lane & 3) * 8;  // staging lane map

  // 4 gl_lds per wave per stage (j in {wave, wave+4} x {A,B}) -> vmcnt unit 4.
  auto stage = [&](int buf, int k0) {
#pragma unroll
    for (int j = wave; j < 8; j += 4) {
      gl_lds16(A + (size_t)(m0 + j * 16 + srow) * K + k0 + scol, &As[buf][j * 512]);
      gl_lds16(B + (size_t)(n0 + j * 16 + srow) * K + k0 + scol, &Bs[buf][j * 512]);
    }
  };

  f32x4 acc[4][4] = {};
  const int nk = K >> 5;
  stage(0, 0);
  stage(1, 32);

  int cur = 0, pre = 2;
  for (int kt = 0; kt < nk; ++kt) {
    if (kt + 1 < nk) asm volatile("s_waitcnt vmcnt(4)" ::: "memory");
    else             asm volatile("s_waitcnt vmcnt(0)" ::: "memory");
    __builtin_amdgcn_s_barrier();
    __builtin_amdgcn_sched_barrier(0);
    if (kt + 2 < nk) stage(pre, (kt + 2) * 32);

    bf16x8 af[4], bfr[4];
#pragma unroll
    for (int s = 0; s < 4; ++s) {
      af[s]  = *(const bf16x8*)(&As[cur][(wm * 64 + s * 16 + l16) * 32 + quad * 8]);
      bfr[s] = *(const bf16x8*)(&Bs[cur][(wn * 64 + s * 16 + l16) * 32 + quad * 8]);
    }
#pragma unroll
    for (int ms = 0; ms < 4; ++ms)
#pragma unroll
      for (int ns = 0; ns < 4; ++ns)
        acc[ms][ns] = __builtin_amdgcn_mfma_f32_16x16x32_bf16(
            af[ms], bfr[ns], acc[ms][ns], 0, 0, 0);

    cur = (cur == 2) ? 0 : cur + 1;
    pre = (pre == 2) ? 0 : pre + 1;
  }

#pragma unroll
  for (int ms = 0; ms < 4; ++ms)
#pragma unroll
    for (int ns = 0; ns < 4; ++ns)
#pragma unroll
      for (int r = 0; r < 4; ++r) {
        int row = m0 + wm * 64 + ms * 16 + quad * 4 + r;
        int col = n0 + wn * 64 + ns * 16 + l16;
        float v = acc[ms][ns][r];
        if (bias_mode == 1) v += bias[col];
        else if (bias_mode == 2) v += bias[row];
        C[(size_t)row * N + col] = (TC)v;
      }
}

// ---------------------------------------------------------------------------
// Fused QKV GEMM (R8-verified split epilogue + R9 pipelined main loop).
// A = x (4096x2048), B = [Wq;Wk;Wv] (4096x2048 contiguous). Grid (32,32).
// bx<24 -> q/k row-major; bx>=24 -> v written TRANSPOSED from registers
// (bf16x4 = 4 consecutive s per store; block covers full 64B lines).
// ---------------------------------------------------------------------------
__global__ __launch_bounds__(256) void gemm_qkv(
    const __bf16* __restrict__ A,   // x: 4096 x 2048
    const __bf16* __restrict__ B,   // [Wq;Wk;Wv]: 4096 x 2048
    const float* __restrict__ bq, const float* __restrict__ bk,
    const float* __restrict__ bv,
    __bf16* __restrict__ qo,        // 4096 x 2048 (S x NH x DH)
    __bf16* __restrict__ ko,        // 4096 x 1024 (S x KVH x DH)
    __bf16* __restrict__ vto)       // 1024 x 4096 (KVH x DH x S)
{
  __shared__ __attribute__((aligned(16))) __bf16 As[3][128 * 32];
  __shared__ __attribute__((aligned(16))) __bf16 Bs[3][128 * 32];
  const int wave = threadIdx.x >> 6, lane = threadIdx.x & 63;
  const int quad = lane >> 4, l16 = lane & 15;
  const int wm = wave >> 1, wn = wave & 1;
  const int m0 = blockIdx.y * 128, n0 = blockIdx.x * 128;
  const int srow = lane >> 2, scol = (lane & 3) * 8;
  const int K = HID;

  auto stage = [&](int buf, int k0) {
#pragma unroll
    for (int j = wave; j < 8; j += 4) {
      gl_lds16(A + (size_t)(m0 + j * 16 + srow) * K + k0 + scol, &As[buf][j * 512]);
      gl_lds16(B + (size_t)(n0 + j * 16 + srow) * K + k0 + scol, &Bs[buf][j * 512]);
    }
  };

  f32x4 acc[4][4] = {};
  const int nk = K >> 5;   // 64 K-steps
  stage(0, 0);
  stage(1, 32);

  int cur = 0, pre = 2;
  for (int kt = 0; kt < nk; ++kt) {
    if (kt + 1 < nk) asm volatile("s_waitcnt vmcnt(4)" ::: "memory");
    else             asm volatile("s_waitcnt vmcnt(0)" ::: "memory");
    __builtin_amdgcn_s_barrier();
    __builtin_amdgcn_sched_barrier(0);
    if (kt + 2 < nk) stage(pre, (kt + 2) * 32);

    bf16x8 af[4], bfr[4];
#pragma unroll
    for (int s = 0; s < 4; ++s) {
      af[s]  = *(const bf16x8*)(&As[cur][(wm * 64 + s * 16 + l16) * 32 + quad * 8]);
      bfr[s] = *(const bf16x8*)(&Bs[cur][(wn * 64 + s * 16 + l16) * 32 + quad * 8]);
    }
#pragma unroll
    for (int ms = 0; ms < 4; ++ms)
#pragma unroll
      for (int ns = 0; ns < 4; ++ns)
        acc[ms][ns] = __builtin_amdgcn_mfma_f32_16x16x32_bf16(
            af[ms], bfr[ns], acc[ms][ns], 0, 0, 0);

    cur = (cur == 2) ? 0 : cur + 1;
    pre = (pre == 2) ? 0 : pre + 1;
  }

  if (blockIdx.x < 24) {
    // ---- q / k region: coalesced row-major store ----
#pragma unroll
    for (int ms = 0; ms < 4; ++ms)
#pragma unroll
      for (int ns = 0; ns < 4; ++ns)
#pragma unroll
        for (int r = 0; r < 4; ++r) {
          int row = m0 + wm * 64 + ms * 16 + quad * 4 + r;
          int col = n0 + wn * 64 + ns * 16 + l16;
          float v = acc[ms][ns][r];
          if (col < 2048) { v += bq[col];        qo[(size_t)row * HID + col] = (__bf16)v; }
          else            { v += bk[col - 2048]; ko[(size_t)row * (KVH * DH) + (col - 2048)] = (__bf16)v; }
        }
  } else {
    // ---- v region: transposed register scatter (bf16x4 = 4 consecutive s) --
#pragma unroll
    for (int ms = 0; ms < 4; ++ms)
#pragma unroll
      for (int ns = 0; ns < 4; ++ns) {
        int vr = n0 - 3072 + wn * 64 + ns * 16 + l16;   // 0..1023 = kvh*DH+d
        int s0 = m0 + wm * 64 + ms * 16 + quad * 4;
        float b = bv[vr];
        bf16x4 p;
#pragma unroll
        for (int r = 0; r < 4; ++r) p[r] = (__bf16)(acc[ms][ns][r] + b);
        *(bf16x4*)(vto + (size_t)vr * S_LEN + s0) = p;
      }
  }
}

// ---------------------------------------------------------------------------
// Per-head RMSNorm (D=128) + RoPE, in-place on q,k (bf16). One wave/(s,head).
// SCALE*LOG2E folded into q output: attn scores land in log2 domain so
// softmax uses raw v_exp_f32 (2^x) with no per-element multiply.
// ---------------------------------------------------------------------------
__global__ __launch_bounds__(256) void rmsnorm_rope(
    __bf16* __restrict__ q, __bf16* __restrict__ k,
    const float* __restrict__ cosb, const float* __restrict__ sinb,
    const float* __restrict__ qw, const float* __restrict__ kw)
{
  const int wave = threadIdx.x >> 6;
  const int lane = threadIdx.x & 63;
  const int row = blockIdx.x * 4 + wave;
  const int s   = row / (NH + KVH);
  const int idx = row % (NH + KVH);

  __bf16* base;
  const float* w;
  float oscale;
  if (idx < NH) { base = q + ((size_t)s * NH + idx) * DH;         w = qw; oscale = SCALE * LOG2E; }
  else          { base = k + ((size_t)s * KVH + (idx - NH)) * DH; w = kw; oscale = 1.0f; }

  float x1 = (float)base[lane];
  float x2 = (float)base[lane + 64];
  float ss = x1 * x1 + x2 * x2;
#pragma unroll
  for (int m = 1; m < 64; m <<= 1) ss += __shfl_xor(ss, m, 64);
  float inv = rsqrtf(ss * (1.0f / 128.0f) + EPS);

  float xh1 = x1 * inv * w[lane];
  float xh2 = x2 * inv * w[lane + 64];
  const float* cs = cosb + (size_t)s * DH;
  const float* sn = sinb + (size_t)s * DH;
  base[lane]      = (__bf16)((xh1 * cs[lane]      - xh2 * sn[lane])      * oscale);
  base[lane + 64] = (__bf16)((xh2 * cs[lane + 64] + xh1 * sn[lane + 64]) * oscale);
}

// ---------------------------------------------------------------------------
// Flash attention v7 (R6-verified, 152us): causal, GQA reps=2. Grid (32, NH),
// block 256 (4 waves), triangle pairing {bx, 63-bx} -> uniform 65 k-tiles.
//  - double-buffered K/V, single barrier/tile, prefetch-over-compute.
//  - exp2-domain softmax (LOG2E pre-folded into q); T13 defer-max (THR=8).
//  - both-sides XOR swizzle on Ks/Vs (rule #21); diagonal-only mask.
//  - per-lane partial lrun, single epilogue reduce.
// ---------------------------------------------------------------------------
__global__ __launch_bounds__(256) void attn2(
    const __bf16* __restrict__ q,   // S x NH x DH  (pre-scaled by SCALE*LOG2E)
    const __bf16* __restrict__ k,   // S x KVH x DH
    const __bf16* __restrict__ vt,  // KVH x DH x S
    __bf16* __restrict__ o)         // S x NH x DH
{
  __shared__ __attribute__((aligned(16))) __bf16 Ks[2][64 * DH];  // 32KB swz
  __shared__ __attribute__((aligned(16))) __bf16 Vs[2][DH * 64];  // 32KB swz
  __shared__ __attribute__((aligned(16))) __bf16 pl[4][16 * 72];  // 9KB
  const int wave = threadIdx.x >> 6, lane = threadIdx.x & 63;
  const int quad = lane >> 4, l16 = lane & 15;
  const int h = blockIdx.y, kvh = h >> 1;

  const __bf16* kh = k + (size_t)kvh * DH;           // row s at + s*KVH*DH
  const __bf16* vh = vt + (size_t)kvh * DH * S_LEN;  // row d at + d*S_LEN

  // Loop-invariant staging lane offsets (4 K-issues + 4 V-issues per wave).
  int krow[4], kcol[4], vrow[4], vcol[4];
#pragma unroll
  for (int i = 0; i < 4; ++i) {
    int j = wave + i * 4;
    int r = j * 4 + (lane >> 4);
    int cbK = ((lane & 15) * 16) ^ ((r & 7) << 4);
    krow[i] = r; kcol[i] = cbK >> 1;
    int d = j * 8 + (lane >> 3);
    int cbV = ((lane & 7) * 16) ^ ((d & 7) << 4);
    vrow[i] = d; vcol[i] = cbV >> 1;
  }
  auto stage = [&](int buf, int k0) {
#pragma unroll
    for (int i = 0; i < 4; ++i)
      gl_lds16(kh + (size_t)(k0 + krow[i]) * (KVH * DH) + kcol[i],
               &Ks[buf][(wave + i * 4) * 512]);
#pragma unroll
    for (int i = 0; i < 4; ++i)
      gl_lds16(vh + (size_t)vrow[i] * S_LEN + k0 + vcol[i],
               &Vs[buf][(wave + i * 4) * 512]);
  };

  for (int phase = 0; phase < 2; ++phase) {
    const int qt = phase == 0 ? (int)blockIdx.x : 63 - (int)blockIdx.x;
    const int qbase = qt * 64 + wave * 16;

    bf16x8 qa[4];
    const __bf16* qrow = q + ((size_t)(qbase + l16) * NH + h) * DH + quad * 8;
#pragma unroll
    for (int c = 0; c < 4; ++c) qa[c] = *(const bf16x8*)(qrow + c * 32);

    f32x4 oacc[8] = {};
    float mrun[4], lrun[4];  // lrun = per-lane PARTIAL row-sum
#pragma unroll
    for (int r = 0; r < 4; ++r) { mrun[r] = -3.0e38f; lrun[r] = 0.0f; }

    __syncthreads();   // prev phase's last reads done before restage
    stage(0, 0);       // prologue

    for (int kt = 0; kt <= qt; ++kt) {
      const int cur = kt & 1;
      const int k0 = kt * 64;
      __syncthreads();
      if (kt < qt) stage(cur ^ 1, k0 + 64);  // prefetch flies over compute

      const char* ksb = (const char*)Ks[cur];
      const char* vsb = (const char*)Vs[cur];

      // ---- scores: 4 col-subtiles x 4 d-chunks (swizzled ds_read) ----
      f32x4 sc[4] = {};
#pragma unroll
      for (int tt = 0; tt < 4; ++tt) {
        const int row = tt * 16 + l16;
        const int swz = (row & 7) << 4;
#pragma unroll
        for (int c = 0; c < 4; ++c) {
          bf16x8 bk = *(const bf16x8*)(ksb + row * 256 + ((c * 64 + quad * 16) ^ swz));
          sc[tt] = __builtin_amdgcn_mfma_f32_16x16x32_bf16(qa[c], bk, sc[tt], 0, 0, 0);
        }
      }
      // ---- causal mask: only the diagonal tile ----
      if (kt == qt) {
#pragma unroll
        for (int tt = 0; tt < 4; ++tt)
#pragma unroll
          for (int r = 0; r < 4; ++r) {
            int col = k0 + tt * 16 + l16;
            int row = qbase + quad * 4 + r;
            if (col > row) sc[tt][r] = -3.0e38f;
          }
      }
      // ---- online softmax (log2 domain): T13 defer-max + deferred l-reduce --
      float pmax[4];
      bool defer = true;
#pragma unroll
      for (int r = 0; r < 4; ++r) {
        float mx = fmaxf(fmaxf(sc[0][r], sc[1][r]), fmaxf(sc[2][r], sc[3][r]));
        pmax[r] = mx;
        defer = defer && (mx - mrun[r] <= 8.0f);
      }
      if (__all(defer)) {
#pragma unroll
        for (int r = 0; r < 4; ++r) {
          float s0 = EXP2(sc[0][r] - mrun[r]);
          float s1 = EXP2(sc[1][r] - mrun[r]);
          float s2 = EXP2(sc[2][r] - mrun[r]);
          float s3 = EXP2(sc[3][r] - mrun[r]);
          sc[0][r] = s0; sc[1][r] = s1; sc[2][r] = s2; sc[3][r] = s3;
          lrun[r] += (s0 + s1) + (s2 + s3);   // per-lane partial
        }
      } else {
#pragma unroll
        for (int r = 0; r < 4; ++r) {
          float mx = pmax[r];
#pragma unroll
          for (int msk = 1; msk < 16; msk <<= 1) mx = fmaxf(mx, __shfl_xor(mx, msk, 64));
          float mnew = fmaxf(mrun[r], mx);     // uniform within 16-lane group
          float sum = 0.0f;
#pragma unroll
          for (int tt = 0; tt < 4; ++tt) {
            float p = EXP2(sc[tt][r] - mnew);
            sc[tt][r] = p;
            sum += p;
          }
          float alpha = EXP2(mrun[r] - mnew);  // uniform -> partial-scale ok
          lrun[r] = lrun[r] * alpha + sum;
          mrun[r] = mnew;
#pragma unroll
          for (int c = 0; c < 8; ++c) oacc[c][r] *= alpha;
        }
      }
      // ---- P: C-layout -> A-layout via per-wave slab (stride 72) ----
#pragma unroll
      for (int tt = 0; tt < 4; ++tt)
#pragma unroll
        for (int r = 0; r < 4; ++r)
          pl[wave][(quad * 4 + r) * 72 + tt * 16 + l16] = (__bf16)sc[tt][r];
      bf16x8 pa[2];
#pragma unroll
      for (int kc = 0; kc < 2; ++kc)
        pa[kc] = *(const bf16x8*)(pl[wave] + l16 * 72 + kc * 32 + quad * 8);
      // ---- PV: 8 d-chunks x 2 k-chunks (swizzled ds_read) ----
#pragma unroll
      for (int c = 0; c < 8; ++c)
#pragma unroll
        for (int kc = 0; kc < 2; ++kc) {
          const int d = c * 16 + l16;
          bf16x8 bv = *(const bf16x8*)(
              vsb + d * 128 + ((kc * 64 + quad * 16) ^ ((d & 7) << 4)));
          oacc[c] = __builtin_amdgcn_mfma_f32_16x16x32_bf16(pa[kc], bv, oacc[c], 0, 0, 0);
        }
    }

    // ---- epilogue: single l-reduce across 16-lane group, then store ----
#pragma unroll
    for (int r = 0; r < 4; ++r) {
#pragma unroll
      for (int msk = 1; msk < 16; msk <<= 1) lrun[r] += __shfl_xor(lrun[r], msk, 64);
      lrun[r] = 1.0f / lrun[r];
    }
#pragma unroll
    for (int c = 0; c < 8; ++c)
#pragma unroll
      for (int r = 0; r < 4; ++r) {
        int row = qbase + quad * 4 + r;
        o[((size_t)row * NH + h) * DH + c * 16 + l16] = (__bf16)(oacc[c][r] * lrun[r]);
      }
  }
}

// ---------------------------------------------------------------------------
extern "C" void kernel_launch(void* const* d_in, const int* in_sizes, int n_in,
                              void* d_out, int out_size, void* d_ws, size_t ws_size,
                              hipStream_t stream) {
  const float* x    = (const float*)d_in[0];
  const float* cosb = (const float*)d_in[1];
  const float* sinb = (const float*)d_in[2];
  // d_in[3] = mask (causal, reimplemented)
  const float* Wq  = (const float*)d_in[4];
  const float* bq  = (const float*)d_in[5];
  const float* Wk  = (const float*)d_in[6];
  const float* bk  = (const float*)d_in[7];
  const float* Wv  = (const float*)d_in[8];
  const float* bv  = (const float*)d_in[9];
  const float* Wo  = (const float*)d_in[10];
  const float* qnw = (const float*)d_in[11];
  const float* knw = (const float*)d_in[12];
  float* out = (float*)d_out;  // 4096x2048 fp32

  // ws (48 MB peak):
  char* ws = (char*)d_ws;
  __bf16* xb    = (__bf16*)(ws);                // 16 MB x bf16 (dies after qkv-GEMM)
  __bf16* Wqb   = (__bf16*)(ws + (16u << 20));  //  8 MB  [Wq;Wk;Wv] contiguous
  __bf16* Wkb   = (__bf16*)(ws + (24u << 20));  //  4 MB  16MB B for fused GEMM
  __bf16* Wvb   = (__bf16*)(ws + (28u << 20));  //  4 MB
  __bf16* kbuf  = (__bf16*)(ws + (32u << 20));  //  8 MB S x KVH x DH
  __bf16* vtbuf = (__bf16*)(ws + (40u << 20));  //  8 MB KVH x DH x S
  __bf16* Wob   = (__bf16*)(ws + (16u << 20));  //  8 MB (reuses Wqb slot)
  __bf16* ao    = (__bf16*)(ws);                // 16 MB attn out (reuses xb slot)
  // d_out doubles as scratch until the final GEMM:
  __bf16* qbuf = (__bf16*)d_out;                // 16 MB S x NH x DH

  dim3 blk(256);
  // fp32 -> bf16 converts
  f2b4<<<dim3(8192), blk, 0, stream>>>(x,  xb,  2097152);
  f2b4<<<dim3(4096), blk, 0, stream>>>(Wq, Wqb, 1048576);
  f2b4<<<dim3(2048), blk, 0, stream>>>(Wk, Wkb, 524288);
  f2b4<<<dim3(2048), blk, 0, stream>>>(Wv, Wvb, 524288);
  // fused q|k|v GEMM: x @ [Wq;Wk;Wv]^T, N=4096, 1024 blocks = 4/CU.
  gemm_qkv<<<dim3(32, 32), blk, 0, stream>>>(
      xb, Wqb, bq, bk, bv, qbuf, kbuf, vtbuf);
  // rmsnorm + rope (in place; folds SCALE*LOG2E into q)
  rmsnorm_rope<<<dim3(S_LEN * (NH + KVH) / 4), blk, 0, stream>>>(
      qbuf, kbuf, cosb, sinb, qnw, knw);
  // Wo convert into dead Wqb slot
  f2b4<<<dim3(4096), blk, 0, stream>>>(Wo, Wob, 1048576);
  // attention -> ao (directly into dead xb slot)
  attn2<<<dim3(32, NH), blk, 0, stream>>>(qbuf, kbuf, vtbuf, ao);
  // out = ao @ Wo^T  (4096x2048, fp32 epilogue into full d_out)
  gemm128<float><<<dim3(16, 32), blk, 0, stream>>>(ao, Wob, nullptr, out, HID, HID, 0);
}

// Round 10
// 465.957 us; speedup vs baseline: 1.3733x; 1.0210x over previous
//
#include <hip/hip_runtime.h>
#include <hip/hip_bf16.h>
#include <stdint.h>

#define S_LEN 4096
#define HID 2048
#define NH 16
#define KVH 8
#define DH 128
#define EPS 1e-6f
#define SCALE 0.08838834764831845f  // 128^-0.5
#define LOG2E 1.4426950408889634f

#if __has_builtin(__builtin_amdgcn_exp2f)
#define EXP2(x) __builtin_amdgcn_exp2f(x)
#else
#define EXP2(x) exp2f(x)
#endif

typedef __bf16 bf16x8 __attribute__((ext_vector_type(8)));
typedef __bf16 bf16x4 __attribute__((ext_vector_type(4)));
typedef float f32x4 __attribute__((ext_vector_type(4)));

// Async global->LDS, 16B per lane. LDS dest must be wave-uniform base;
// lane i lands at dst + i*16B (m97/m104-verified semantics).
__device__ inline void gl_lds16(const __bf16* g, __bf16* l) {
  __builtin_amdgcn_global_load_lds(
      (const __attribute__((address_space(1))) void*)g,
      (__attribute__((address_space(3))) void*)l, 16, 0, 0);
}

// ---------------------------------------------------------------------------
// fp32 -> bf16 bulk convert (4 elems/thread).
// ---------------------------------------------------------------------------
__global__ __launch_bounds__(256) void f2b4(
    const float* __restrict__ in, __bf16* __restrict__ out, int n4) {
  int i = blockIdx.x * 256 + threadIdx.x;
  if (i < n4) {
    float4 v = ((const float4*)in)[i];
    bf16x4 o;
    o[0] = (__bf16)v.x; o[1] = (__bf16)v.y; o[2] = (__bf16)v.z; o[3] = (__bf16)v.w;
    ((bf16x4*)out)[i] = o;
  }
}

// ---------------------------------------------------------------------------
// NT GEMM, 128x128 tile, BK=32, 4 waves. R9 pipeline: triple-buffered LDS,
// 2-tile lead, counted vmcnt (never 0 in main loop), raw s_barrier.
// Used for the final GEMM only (512 blocks = 2/CU grid-limited; LDS 48KB
// allows 3/CU so no occupancy loss, no tail).
// bias_mode: 0 none, 1 per-col, 2 per-row.
// ---------------------------------------------------------------------------
template <typename TC>
__global__ __launch_bounds__(256) void gemm128(
    const __bf16* __restrict__ A, const __bf16* __restrict__ B,
    const float* __restrict__ bias, TC* __restrict__ C,
    int N, int K, int bias_mode)
{
  __shared__ __attribute__((aligned(16))) __bf16 As[3][128 * 32];  // 24KB
  __shared__ __attribute__((aligned(16))) __bf16 Bs[3][128 * 32];  // 24KB
  const int wave = threadIdx.x >> 6, lane = threadIdx.x & 63;
  const int quad = lane >> 4, l16 = lane & 15;
  const int wm = wave >> 1, wn = wave & 1;
  const int m0 = blockIdx.y * 128, n0 = blockIdx.x * 128;
  const int srow = lane >> 2, scol = (lane & 3) * 8;  // staging lane map

  auto stage = [&](int buf, int k0) {
#pragma unroll
    for (int j = wave; j < 8; j += 4) {
      gl_lds16(A + (size_t)(m0 + j * 16 + srow) * K + k0 + scol, &As[buf][j * 512]);
      gl_lds16(B + (size_t)(n0 + j * 16 + srow) * K + k0 + scol, &Bs[buf][j * 512]);
    }
  };

  f32x4 acc[4][4] = {};
  const int nk = K >> 5;
  stage(0, 0);
  stage(1, 32);

  int cur = 0, pre = 2;
  for (int kt = 0; kt < nk; ++kt) {
    if (kt + 1 < nk) asm volatile("s_waitcnt vmcnt(4)" ::: "memory");
    else             asm volatile("s_waitcnt vmcnt(0)" ::: "memory");
    __builtin_amdgcn_s_barrier();
    __builtin_amdgcn_sched_barrier(0);
    if (kt + 2 < nk) stage(pre, (kt + 2) * 32);

    bf16x8 af[4], bfr[4];
#pragma unroll
    for (int s = 0; s < 4; ++s) {
      af[s]  = *(const bf16x8*)(&As[cur][(wm * 64 + s * 16 + l16) * 32 + quad * 8]);
      bfr[s] = *(const bf16x8*)(&Bs[cur][(wn * 64 + s * 16 + l16) * 32 + quad * 8]);
    }
#pragma unroll
    for (int ms = 0; ms < 4; ++ms)
#pragma unroll
      for (int ns = 0; ns < 4; ++ns)
        acc[ms][ns] = __builtin_amdgcn_mfma_f32_16x16x32_bf16(
            af[ms], bfr[ns], acc[ms][ns], 0, 0, 0);

    cur = (cur == 2) ? 0 : cur + 1;
    pre = (pre == 2) ? 0 : pre + 1;
  }

#pragma unroll
  for (int ms = 0; ms < 4; ++ms)
#pragma unroll
    for (int ns = 0; ns < 4; ++ns)
#pragma unroll
      for (int r = 0; r < 4; ++r) {
        int row = m0 + wm * 64 + ms * 16 + quad * 4 + r;
        int col = n0 + wn * 64 + ns * 16 + l16;
        float v = acc[ms][ns][r];
        if (bias_mode == 1) v += bias[col];
        else if (bias_mode == 2) v += bias[row];
        C[(size_t)row * N + col] = (TC)v;
      }
}

// ---------------------------------------------------------------------------
// R10: fused QKV GEMM, 256x256 tile (m230-V0 structure: 682 TF refcheck'd
// plain-HIP at this tile+sync). 512 threads = 8 waves (2M x 4N), BK=64,
// double-buffered 128KB LDS, 1 block/CU, grid (16,16) = 256 blocks = exactly
// one generation (R9 lesson: no ragged tail). R8's proven single-barrier
// sync: __syncthreads drains own vmcnt + publishes; stage(t+1) issued after,
// lands during the 64-MFMA compute phase.
// T2-style XOR swizzle (both sides, rule #21): staging pre-swizzles the
// GLOBAL col by ((row&7)<<4) bytes, LDS dest linear; reads XOR the same ->
// read swz reduces to (l16&7)<<4 (lane-only, free).
// Output regions (256-col blocks never straddle): bx<8 q, 8..11 k (row-major
// + bias), 12..15 v written TRANSPOSED from registers (bf16x4 = 4 consecutive
// s per store; R8-verified pattern).
// ---------------------------------------------------------------------------
__global__ __launch_bounds__(512) void gemm_qkv256(
    const __bf16* __restrict__ A,   // x: 4096 x 2048
    const __bf16* __restrict__ B,   // [Wq;Wk;Wv]: 4096 x 2048
    const float* __restrict__ bq, const float* __restrict__ bk,
    const float* __restrict__ bv,
    __bf16* __restrict__ qo,        // 4096 x 2048 (S x NH x DH)
    __bf16* __restrict__ ko,        // 4096 x 1024 (S x KVH x DH)
    __bf16* __restrict__ vto)       // 1024 x 4096 (KVH x DH x S)
{
  __shared__ __attribute__((aligned(16))) __bf16 Abuf[2][256 * 64];  // 64KB
  __shared__ __attribute__((aligned(16))) __bf16 Bbuf[2][256 * 64];  // 64KB
  const int tid = threadIdx.x;
  const int wid = tid >> 6, lane = tid & 63;
  const int quad = lane >> 4, l16 = lane & 15;
  const int wm = wid >> 2, wn = wid & 3;     // 2 x 4 wave grid
  const int m0 = blockIdx.y * 256, n0 = blockIdx.x * 256;
  const int K = HID;

  // Staging lane map: chunk c covers rows c*64..c*64+63; row = c*64+(tid>>3),
  // 8 lanes per row (16B each). Global col pre-swizzled by ((row&7)<<4) B.
  const int srow  = tid >> 3;                               // 0..63
  const int scole = (((tid & 7) * 16) ^ ((srow & 7) << 4)) >> 1;  // elems

  auto stage = [&](int buf, int k0) {
#pragma unroll
    for (int c = 0; c < 4; ++c) {
      gl_lds16(A + (size_t)(m0 + c * 64 + srow) * K + k0 + scole,
               &Abuf[buf][c * 4096 + wid * 512]);
      gl_lds16(B + (size_t)(n0 + c * 64 + srow) * K + k0 + scole,
               &Bbuf[buf][c * 4096 + wid * 512]);
    }
  };

  f32x4 acc[8][4] = {};          // 128 VGPR accumulator (128x64 per wave)
  const int nk = K >> 6;         // 32 K-tiles of 64
  const int swz = (l16 & 7) << 4;  // read-side XOR (row&7 == l16&7 here)
  stage(0, 0);

  for (int kt = 0; kt < nk; ++kt) {
    const int cur = kt & 1;
    __syncthreads();   // own vmcnt(0) drain (had full compute to land) + bar
    if (kt + 1 < nk) stage(cur ^ 1, (kt + 1) * 64);

    const char* ab = (const char*)Abuf[cur];
    const char* bb = (const char*)Bbuf[cur];
#pragma unroll
    for (int ks = 0; ks < 2; ++ks) {
      bf16x8 af[8], bfr[4];
#pragma unroll
      for (int fr = 0; fr < 8; ++fr) {
        int rl = wm * 128 + fr * 16 + l16;
        af[fr] = *(const bf16x8*)(ab + rl * 128 + ((ks * 64 + quad * 16) ^ swz));
      }
#pragma unroll
      for (int fn = 0; fn < 4; ++fn) {
        int rl = wn * 64 + fn * 16 + l16;
        bfr[fn] = *(const bf16x8*)(bb + rl * 128 + ((ks * 64 + quad * 16) ^ swz));
      }
#pragma unroll
      for (int fr = 0; fr < 8; ++fr)
#pragma unroll
        for (int fn = 0; fn < 4; ++fn)
          acc[fr][fn] = __builtin_amdgcn_mfma_f32_16x16x32_bf16(
              af[fr], bfr[fn], acc[fr][fn], 0, 0, 0);
    }
  }

  if (blockIdx.x < 12) {
    // ---- q / k region: coalesced row-major store + bias ----
#pragma unroll
    for (int fr = 0; fr < 8; ++fr)
#pragma unroll
      for (int fn = 0; fn < 4; ++fn)
#pragma unroll
        for (int r = 0; r < 4; ++r) {
          int row = m0 + wm * 128 + fr * 16 + quad * 4 + r;
          int col = n0 + wn * 64 + fn * 16 + l16;
          float v = acc[fr][fn][r];
          if (col < 2048) { v += bq[col];        qo[(size_t)row * HID + col] = (__bf16)v; }
          else            { v += bk[col - 2048]; ko[(size_t)row * (KVH * DH) + (col - 2048)] = (__bf16)v; }
        }
  } else {
    // ---- v region: transposed register scatter (4 consecutive s / store) --
#pragma unroll
    for (int fr = 0; fr < 8; ++fr)
#pragma unroll
      for (int fn = 0; fn < 4; ++fn) {
        int vr = n0 - 3072 + wn * 64 + fn * 16 + l16;   // 0..1023 = kvh*DH+d
        int s0 = m0 + wm * 128 + fr * 16 + quad * 4;
        float b = bv[vr];
        bf16x4 p;
#pragma unroll
        for (int r = 0; r < 4; ++r) p[r] = (__bf16)(acc[fr][fn][r] + b);
        *(bf16x4*)(vto + (size_t)vr * S_LEN + s0) = p;
      }
  }
}

// ---------------------------------------------------------------------------
// Per-head RMSNorm (D=128) + RoPE, in-place on q,k (bf16). One wave/(s,head).
// SCALE*LOG2E folded into q output: attn scores land in log2 domain so
// softmax uses raw v_exp_f32 (2^x) with no per-element multiply.
// ---------------------------------------------------------------------------
__global__ __launch_bounds__(256) void rmsnorm_rope(
    __bf16* __restrict__ q, __bf16* __restrict__ k,
    const float* __restrict__ cosb, const float* __restrict__ sinb,
    const float* __restrict__ qw, const float* __restrict__ kw)
{
  const int wave = threadIdx.x >> 6;
  const int lane = threadIdx.x & 63;
  const int row = blockIdx.x * 4 + wave;
  const int s   = row / (NH + KVH);
  const int idx = row % (NH + KVH);

  __bf16* base;
  const float* w;
  float oscale;
  if (idx < NH) { base = q + ((size_t)s * NH + idx) * DH;         w = qw; oscale = SCALE * LOG2E; }
  else          { base = k + ((size_t)s * KVH + (idx - NH)) * DH; w = kw; oscale = 1.0f; }

  float x1 = (float)base[lane];
  float x2 = (float)base[lane + 64];
  float ss = x1 * x1 + x2 * x2;
#pragma unroll
  for (int m = 1; m < 64; m <<= 1) ss += __shfl_xor(ss, m, 64);
  float inv = rsqrtf(ss * (1.0f / 128.0f) + EPS);

  float xh1 = x1 * inv * w[lane];
  float xh2 = x2 * inv * w[lane + 64];
  const float* cs = cosb + (size_t)s * DH;
  const float* sn = sinb + (size_t)s * DH;
  base[lane]      = (__bf16)((xh1 * cs[lane]      - xh2 * sn[lane])      * oscale);
  base[lane + 64] = (__bf16)((xh2 * cs[lane + 64] + xh1 * sn[lane + 64]) * oscale);
}

// ---------------------------------------------------------------------------
// Flash attention v7 (R6-verified, 152us): causal, GQA reps=2. Grid (32, NH),
// block 256 (4 waves), triangle pairing {bx, 63-bx} -> uniform 65 k-tiles.
//  - double-buffered K/V, single barrier/tile, prefetch-over-compute.
//  - exp2-domain softmax (LOG2E pre-folded into q); T13 defer-max (THR=8).
//  - both-sides XOR swizzle on Ks/Vs (rule #21); diagonal-only mask.
//  - per-lane partial lrun, single epilogue reduce.
// ---------------------------------------------------------------------------
__global__ __launch_bounds__(256) void attn2(
    const __bf16* __restrict__ q,   // S x NH x DH  (pre-scaled by SCALE*LOG2E)
    const __bf16* __restrict__ k,   // S x KVH x DH
    const __bf16* __restrict__ vt,  // KVH x DH x S
    __bf16* __restrict__ o)         // S x NH x DH
{
  __shared__ __attribute__((aligned(16))) __bf16 Ks[2][64 * DH];  // 32KB swz
  __shared__ __attribute__((aligned(16))) __bf16 Vs[2][DH * 64];  // 32KB swz
  __shared__ __attribute__((aligned(16))) __bf16 pl[4][16 * 72];  // 9KB
  const int wave = threadIdx.x >> 6, lane = threadIdx.x & 63;
  const int quad = lane >> 4, l16 = lane & 15;
  const int h = blockIdx.y, kvh = h >> 1;

  const __bf16* kh = k + (size_t)kvh * DH;           // row s at + s*KVH*DH
  const __bf16* vh = vt + (size_t)kvh * DH * S_LEN;  // row d at + d*S_LEN

  // Loop-invariant staging lane offsets (4 K-issues + 4 V-issues per wave).
  int krow[4], kcol[4], vrow[4], vcol[4];
#pragma unroll
  for (int i = 0; i < 4; ++i) {
    int j = wave + i * 4;
    int r = j * 4 + (lane >> 4);
    int cbK = ((lane & 15) * 16) ^ ((r & 7) << 4);
    krow[i] = r; kcol[i] = cbK >> 1;
    int d = j * 8 + (lane >> 3);
    int cbV = ((lane & 7) * 16) ^ ((d & 7) << 4);
    vrow[i] = d; vcol[i] = cbV >> 1;
  }
  auto stage = [&](int buf, int k0) {
#pragma unroll
    for (int i = 0; i < 4; ++i)
      gl_lds16(kh + (size_t)(k0 + krow[i]) * (KVH * DH) + kcol[i],
               &Ks[buf][(wave + i * 4) * 512]);
#pragma unroll
    for (int i = 0; i < 4; ++i)
      gl_lds16(vh + (size_t)vrow[i] * S_LEN + k0 + vcol[i],
               &Vs[buf][(wave + i * 4) * 512]);
  };

  for (int phase = 0; phase < 2; ++phase) {
    const int qt = phase == 0 ? (int)blockIdx.x : 63 - (int)blockIdx.x;
    const int qbase = qt * 64 + wave * 16;

    bf16x8 qa[4];
    const __bf16* qrow = q + ((size_t)(qbase + l16) * NH + h) * DH + quad * 8;
#pragma unroll
    for (int c = 0; c < 4; ++c) qa[c] = *(const bf16x8*)(qrow + c * 32);

    f32x4 oacc[8] = {};
    float mrun[4], lrun[4];  // lrun = per-lane PARTIAL row-sum
#pragma unroll
    for (int r = 0; r < 4; ++r) { mrun[r] = -3.0e38f; lrun[r] = 0.0f; }

    __syncthreads();   // prev phase's last reads done before restage
    stage(0, 0);       // prologue

    for (int kt = 0; kt <= qt; ++kt) {
      const int cur = kt & 1;
      const int k0 = kt * 64;
      __syncthreads();
      if (kt < qt) stage(cur ^ 1, k0 + 64);  // prefetch flies over compute

      const char* ksb = (const char*)Ks[cur];
      const char* vsb = (const char*)Vs[cur];

      // ---- scores: 4 col-subtiles x 4 d-chunks (swizzled ds_read) ----
      f32x4 sc[4] = {};
#pragma unroll
      for (int tt = 0; tt < 4; ++tt) {
        const int row = tt * 16 + l16;
        const int swz = (row & 7) << 4;
#pragma unroll
        for (int c = 0; c < 4; ++c) {
          bf16x8 bk = *(const bf16x8*)(ksb + row * 256 + ((c * 64 + quad * 16) ^ swz));
          sc[tt] = __builtin_amdgcn_mfma_f32_16x16x32_bf16(qa[c], bk, sc[tt], 0, 0, 0);
        }
      }
      // ---- causal mask: only the diagonal tile ----
      if (kt == qt) {
#pragma unroll
        for (int tt = 0; tt < 4; ++tt)
#pragma unroll
          for (int r = 0; r < 4; ++r) {
            int col = k0 + tt * 16 + l16;
            int row = qbase + quad * 4 + r;
            if (col > row) sc[tt][r] = -3.0e38f;
          }
      }
      // ---- online softmax (log2 domain): T13 defer-max + deferred l-reduce --
      float pmax[4];
      bool defer = true;
#pragma unroll
      for (int r = 0; r < 4; ++r) {
        float mx = fmaxf(fmaxf(sc[0][r], sc[1][r]), fmaxf(sc[2][r], sc[3][r]));
        pmax[r] = mx;
        defer = defer && (mx - mrun[r] <= 8.0f);
      }
      if (__all(defer)) {
#pragma unroll
        for (int r = 0; r < 4; ++r) {
          float s0 = EXP2(sc[0][r] - mrun[r]);
          float s1 = EXP2(sc[1][r] - mrun[r]);
          float s2 = EXP2(sc[2][r] - mrun[r]);
          float s3 = EXP2(sc[3][r] - mrun[r]);
          sc[0][r] = s0; sc[1][r] = s1; sc[2][r] = s2; sc[3][r] = s3;
          lrun[r] += (s0 + s1) + (s2 + s3);   // per-lane partial
        }
      } else {
#pragma unroll
        for (int r = 0; r < 4; ++r) {
          float mx = pmax[r];
#pragma unroll
          for (int msk = 1; msk < 16; msk <<= 1) mx = fmaxf(mx, __shfl_xor(mx, msk, 64));
          float mnew = fmaxf(mrun[r], mx);     // uniform within 16-lane group
          float sum = 0.0f;
#pragma unroll
          for (int tt = 0; tt < 4; ++tt) {
            float p = EXP2(sc[tt][r] - mnew);
            sc[tt][r] = p;
            sum += p;
          }
          float alpha = EXP2(mrun[r] - mnew);  // uniform -> partial-scale ok
          lrun[r] = lrun[r] * alpha + sum;
          mrun[r] = mnew;
#pragma unroll
          for (int c = 0; c < 8; ++c) oacc[c][r] *= alpha;
        }
      }
      // ---- P: C-layout -> A-layout via per-wave slab (stride 72) ----
#pragma unroll
      for (int tt = 0; tt < 4; ++tt)
#pragma unroll
        for (int r = 0; r < 4; ++r)
          pl[wave][(quad * 4 + r) * 72 + tt * 16 + l16] = (__bf16)sc[tt][r];
      bf16x8 pa[2];
#pragma unroll
      for (int kc = 0; kc < 2; ++kc)
        pa[kc] = *(const bf16x8*)(pl[wave] + l16 * 72 + kc * 32 + quad * 8);
      // ---- PV: 8 d-chunks x 2 k-chunks (swizzled ds_read) ----
#pragma unroll
      for (int c = 0; c < 8; ++c)
#pragma unroll
        for (int kc = 0; kc < 2; ++kc) {
          const int d = c * 16 + l16;
          bf16x8 bv = *(const bf16x8*)(
              vsb + d * 128 + ((kc * 64 + quad * 16) ^ ((d & 7) << 4)));
          oacc[c] = __builtin_amdgcn_mfma_f32_16x16x32_bf16(pa[kc], bv, oacc[c], 0, 0, 0);
        }
    }

    // ---- epilogue: single l-reduce across 16-lane group, then store ----
#pragma unroll
    for (int r = 0; r < 4; ++r) {
#pragma unroll
      for (int msk = 1; msk < 16; msk <<= 1) lrun[r] += __shfl_xor(lrun[r], msk, 64);
      lrun[r] = 1.0f / lrun[r];
    }
#pragma unroll
    for (int c = 0; c < 8; ++c)
#pragma unroll
      for (int r = 0; r < 4; ++r) {
        int row = qbase + quad * 4 + r;
        o[((size_t)row * NH + h) * DH + c * 16 + l16] = (__bf16)(oacc[c][r] * lrun[r]);
      }
  }
}

// ---------------------------------------------------------------------------
extern "C" void kernel_launch(void* const* d_in, const int* in_sizes, int n_in,
                              void* d_out, int out_size, void* d_ws, size_t ws_size,
                              hipStream_t stream) {
  const float* x    = (const float*)d_in[0];
  const float* cosb = (const float*)d_in[1];
  const float* sinb = (const float*)d_in[2];
  // d_in[3] = mask (causal, reimplemented)
  const float* Wq  = (const float*)d_in[4];
  const float* bq  = (const float*)d_in[5];
  const float* Wk  = (const float*)d_in[6];
  const float* bk  = (const float*)d_in[7];
  const float* Wv  = (const float*)d_in[8];
  const float* bv  = (const float*)d_in[9];
  const float* Wo  = (const float*)d_in[10];
  const float* qnw = (const float*)d_in[11];
  const float* knw = (const float*)d_in[12];
  float* out = (float*)d_out;  // 4096x2048 fp32

  // ws (48 MB peak):
  char* ws = (char*)d_ws;
  __bf16* xb    = (__bf16*)(ws);                // 16 MB x bf16 (dies after qkv-GEMM)
  __bf16* Wqb   = (__bf16*)(ws + (16u << 20));  //  8 MB  [Wq;Wk;Wv] contiguous
  __bf16* Wkb   = (__bf16*)(ws + (24u << 20));  //  4 MB  16MB B for fused GEMM
  __bf16* Wvb   = (__bf16*)(ws + (28u << 20));  //  4 MB
  __bf16* kbuf  = (__bf16*)(ws + (32u << 20));  //  8 MB S x KVH x DH
  __bf16* vtbuf = (__bf16*)(ws + (40u << 20));  //  8 MB KVH x DH x S
  __bf16* Wob   = (__bf16*)(ws + (16u << 20));  //  8 MB (reuses Wqb slot)
  __bf16* ao    = (__bf16*)(ws);                // 16 MB attn out (reuses xb slot)
  // d_out doubles as scratch until the final GEMM:
  __bf16* qbuf = (__bf16*)d_out;                // 16 MB S x NH x DH

  dim3 blk(256);
  // fp32 -> bf16 converts
  f2b4<<<dim3(8192), blk, 0, stream>>>(x,  xb,  2097152);
  f2b4<<<dim3(4096), blk, 0, stream>>>(Wq, Wqb, 1048576);
  f2b4<<<dim3(2048), blk, 0, stream>>>(Wk, Wkb, 524288);
  f2b4<<<dim3(2048), blk, 0, stream>>>(Wv, Wvb, 524288);
  // fused q|k|v GEMM: x @ [Wq;Wk;Wv]^T, 256^2 tiles, 256 blocks = 1/CU exact.
  gemm_qkv256<<<dim3(16, 16), dim3(512), 0, stream>>>(
      xb, Wqb, bq, bk, bv, qbuf, kbuf, vtbuf);
  // rmsnorm + rope (in place; folds SCALE*LOG2E into q)
  rmsnorm_rope<<<dim3(S_LEN * (NH + KVH) / 4), blk, 0, stream>>>(
      qbuf, kbuf, cosb, sinb, qnw, knw);
  // Wo convert into dead Wqb slot
  f2b4<<<dim3(4096), blk, 0, stream>>>(Wo, Wob, 1048576);
  // attention -> ao (directly into dead xb slot)
  attn2<<<dim3(32, NH), blk, 0, stream>>>(qbuf, kbuf, vtbuf, ao);
  // out = ao @ Wo^T  (4096x2048, fp32 epilogue into full d_out)
  gemm128<float><<<dim3(16, 32), blk, 0, stream>>>(ao, Wob, nullptr, out, HID, HID, 0);
}

// Round 12
// 448.891 us; speedup vs baseline: 1.4255x; 1.0380x over previous
//
#include <hip/hip_runtime.h>
#include <hip/hip_bf16.h>
#include <stdint.h>

#define S_LEN 4096
#define HID 2048
#define NH 16
#define KVH 8
#define DH 128
#define EPS 1e-6f
#define SCALE 0.08838834764831845f  // 128^-0.5
#define LOG2E 1.4426950408889634f

#if __has_builtin(__builtin_amdgcn_exp2f)
#define EXP2(x) __builtin_amdgcn_exp2f(x)
#else
#define EXP2(x) exp2f(x)
#endif

typedef __bf16 bf16x8 __attribute__((ext_vector_type(8)));
typedef __bf16 bf16x4 __attribute__((ext_vector_type(4)));
typedef float f32x4 __attribute__((ext_vector_type(4)));

// Async global->LDS, 16B per lane. LDS dest must be wave-uniform base;
// lane i lands at dst + i*16B (m97/m104-verified semantics).
__device__ inline void gl_lds16(const __bf16* g, __bf16* l) {
  __builtin_amdgcn_global_load_lds(
      (const __attribute__((address_space(1))) void*)g,
      (__attribute__((address_space(3))) void*)l, 16, 0, 0);
}

// ---------------------------------------------------------------------------
// Merged fp32 -> bf16 convert for {x, Wq, Wk, Wv} in one launch (R11: removes
// 3 launch gaps). Region boundaries in float4 units.
// ---------------------------------------------------------------------------
#define N4_X  2097152
#define N4_WQ 1048576
#define N4_WK  524288
#define N4_WV  524288
#define N4_ALL (N4_X + N4_WQ + N4_WK + N4_WV)   // 4194304

__global__ __launch_bounds__(256) void f2b_all(
    const float* __restrict__ x,  const float* __restrict__ wq,
    const float* __restrict__ wk, const float* __restrict__ wv,
    __bf16* __restrict__ xb,  __bf16* __restrict__ wqb,
    __bf16* __restrict__ wkb, __bf16* __restrict__ wvb) {
  int i = blockIdx.x * 256 + threadIdx.x;
  if (i >= N4_ALL) return;
  const float* src; __bf16* dst; int off;
  if (i < N4_X)                     { src = x;  dst = xb;  off = i; }
  else if (i < N4_X + N4_WQ)        { src = wq; dst = wqb; off = i - N4_X; }
  else if (i < N4_X + N4_WQ + N4_WK){ src = wk; dst = wkb; off = i - N4_X - N4_WQ; }
  else                              { src = wv; dst = wvb; off = i - N4_X - N4_WQ - N4_WK; }
  float4 v = ((const float4*)src)[off];
  bf16x4 o;
  o[0] = (__bf16)v.x; o[1] = (__bf16)v.y; o[2] = (__bf16)v.z; o[3] = (__bf16)v.w;
  ((bf16x4*)dst)[off] = o;
}

__global__ __launch_bounds__(256) void f2b4(
    const float* __restrict__ in, __bf16* __restrict__ out, int n4) {
  int i = blockIdx.x * 256 + threadIdx.x;
  if (i < n4) {
    float4 v = ((const float4*)in)[i];
    bf16x4 o;
    o[0] = (__bf16)v.x; o[1] = (__bf16)v.y; o[2] = (__bf16)v.z; o[3] = (__bf16)v.w;
    ((bf16x4*)out)[i] = o;
  }
}

// ---------------------------------------------------------------------------
// NT GEMM, 128x128 tile, BK=32, 4 waves. R9 pipeline: triple-buffered LDS,
// 2-tile lead, counted vmcnt (never 0 in main loop), raw s_barrier.
// Used for the final GEMM (512 blocks = 2/CU, LDS 48KB -> no occupancy loss).
// bias_mode: 0 none, 1 per-col, 2 per-row.
// ---------------------------------------------------------------------------
template <typename TC>
__global__ __launch_bounds__(256) void gemm128(
    const __bf16* __restrict__ A, const __bf16* __restrict__ B,
    const float* __restrict__ bias, TC* __restrict__ C,
    int N, int K, int bias_mode)
{
  __shared__ __attribute__((aligned(16))) __bf16 As[3][128 * 32];  // 24KB
  __shared__ __attribute__((aligned(16))) __bf16 Bs[3][128 * 32];  // 24KB
  const int wave = threadIdx.x >> 6, lane = threadIdx.x & 63;
  const int quad = lane >> 4, l16 = lane & 15;
  const int wm = wave >> 1, wn = wave & 1;
  const int m0 = blockIdx.y * 128, n0 = blockIdx.x * 128;
  const int srow = lane >> 2, scol = (lane & 3) * 8;  // staging lane map

  auto stage = [&](int buf, int k0) {
#pragma unroll
    for (int j = wave; j < 8; j += 4) {
      gl_lds16(A + (size_t)(m0 + j * 16 + srow) * K + k0 + scol, &As[buf][j * 512]);
      gl_lds16(B + (size_t)(n0 + j * 16 + srow) * K + k0 + scol, &Bs[buf][j * 512]);
    }
  };

  f32x4 acc[4][4] = {};
  const int nk = K >> 5;
  stage(0, 0);
  stage(1, 32);

  int cur = 0, pre = 2;
  for (int kt = 0; kt < nk; ++kt) {
    if (kt + 1 < nk) asm volatile("s_waitcnt vmcnt(4)" ::: "memory");
    else             asm volatile("s_waitcnt vmcnt(0)" ::: "memory");
    __builtin_amdgcn_s_barrier();
    __builtin_amdgcn_sched_barrier(0);
    if (kt + 2 < nk) stage(pre, (kt + 2) * 32);

    bf16x8 af[4], bfr[4];
#pragma unroll
    for (int s = 0; s < 4; ++s) {
      af[s]  = *(const bf16x8*)(&As[cur][(wm * 64 + s * 16 + l16) * 32 + quad * 8]);
      bfr[s] = *(const bf16x8*)(&Bs[cur][(wn * 64 + s * 16 + l16) * 32 + quad * 8]);
    }
#pragma unroll
    for (int ms = 0; ms < 4; ++ms)
#pragma unroll
      for (int ns = 0; ns < 4; ++ns)
        acc[ms][ns] = __builtin_amdgcn_mfma_f32_16x16x32_bf16(
            af[ms], bfr[ns], acc[ms][ns], 0, 0, 0);

    cur = (cur == 2) ? 0 : cur + 1;
    pre = (pre == 2) ? 0 : pre + 1;
  }

#pragma unroll
  for (int ms = 0; ms < 4; ++ms)
#pragma unroll
    for (int ns = 0; ns < 4; ++ns)
#pragma unroll
      for (int r = 0; r < 4; ++r) {
        int row = m0 + wm * 64 + ms * 16 + quad * 4 + r;
        int col = n0 + wn * 64 + ns * 16 + l16;
        float v = acc[ms][ns][r];
        if (bias_mode == 1) v += bias[col];
        else if (bias_mode == 2) v += bias[row];
        C[(size_t)row * N + col] = (TC)v;
      }
}

// ---------------------------------------------------------------------------
// Fused QKV GEMM, 256x256 tile, 8 waves, BK=64, dbuf 128KB LDS, 1 block/CU,
// grid 256 = one generation. Both-sides XOR swizzle. R10-verified correct.
// ---------------------------------------------------------------------------
__global__ __launch_bounds__(512) void gemm_qkv256(
    const __bf16* __restrict__ A,   // x: 4096 x 2048
    const __bf16* __restrict__ B,   // [Wq;Wk;Wv]: 4096 x 2048
    const float* __restrict__ bq, const float* __restrict__ bk,
    const float* __restrict__ bv,
    __bf16* __restrict__ qo,        // 4096 x 2048 (S x NH x DH)
    __bf16* __restrict__ ko,        // 4096 x 1024 (S x KVH x DH)
    __bf16* __restrict__ vto)       // 1024 x 4096 (KVH x DH x S)
{
  __shared__ __attribute__((aligned(16))) __bf16 Abuf[2][256 * 64];  // 64KB
  __shared__ __attribute__((aligned(16))) __bf16 Bbuf[2][256 * 64];  // 64KB
  const int tid = threadIdx.x;
  const int wid = tid >> 6, lane = tid & 63;
  const int quad = lane >> 4, l16 = lane & 15;
  const int wm = wid >> 2, wn = wid & 3;     // 2 x 4 wave grid
  const int m0 = blockIdx.y * 256, n0 = blockIdx.x * 256;
  const int K = HID;

  const int srow  = tid >> 3;                               // 0..63
  const int scole = (((tid & 7) * 16) ^ ((srow & 7) << 4)) >> 1;  // elems

  auto stage = [&](int buf, int k0) {
#pragma unroll
    for (int c = 0; c < 4; ++c) {
      gl_lds16(A + (size_t)(m0 + c * 64 + srow) * K + k0 + scole,
               &Abuf[buf][c * 4096 + wid * 512]);
      gl_lds16(B + (size_t)(n0 + c * 64 + srow) * K + k0 + scole,
               &Bbuf[buf][c * 4096 + wid * 512]);
    }
  };

  f32x4 acc[8][4] = {};
  const int nk = K >> 6;
  const int swz = (l16 & 7) << 4;
  stage(0, 0);

  for (int kt = 0; kt < nk; ++kt) {
    const int cur = kt & 1;
    __syncthreads();
    if (kt + 1 < nk) stage(cur ^ 1, (kt + 1) * 64);

    const char* ab = (const char*)Abuf[cur];
    const char* bb = (const char*)Bbuf[cur];
#pragma unroll
    for (int ks = 0; ks < 2; ++ks) {
      bf16x8 af[8], bfr[4];
#pragma unroll
      for (int fr = 0; fr < 8; ++fr) {
        int rl = wm * 128 + fr * 16 + l16;
        af[fr] = *(const bf16x8*)(ab + rl * 128 + ((ks * 64 + quad * 16) ^ swz));
      }
#pragma unroll
      for (int fn = 0; fn < 4; ++fn) {
        int rl = wn * 64 + fn * 16 + l16;
        bfr[fn] = *(const bf16x8*)(bb + rl * 128 + ((ks * 64 + quad * 16) ^ swz));
      }
#pragma unroll
      for (int fr = 0; fr < 8; ++fr)
#pragma unroll
        for (int fn = 0; fn < 4; ++fn)
          acc[fr][fn] = __builtin_amdgcn_mfma_f32_16x16x32_bf16(
              af[fr], bfr[fn], acc[fr][fn], 0, 0, 0);
    }
  }

  if (blockIdx.x < 12) {
#pragma unroll
    for (int fr = 0; fr < 8; ++fr)
#pragma unroll
      for (int fn = 0; fn < 4; ++fn)
#pragma unroll
        for (int r = 0; r < 4; ++r) {
          int row = m0 + wm * 128 + fr * 16 + quad * 4 + r;
          int col = n0 + wn * 64 + fn * 16 + l16;
          float v = acc[fr][fn][r];
          if (col < 2048) { v += bq[col];        qo[(size_t)row * HID + col] = (__bf16)v; }
          else            { v += bk[col - 2048]; ko[(size_t)row * (KVH * DH) + (col - 2048)] = (__bf16)v; }
        }
  } else {
#pragma unroll
    for (int fr = 0; fr < 8; ++fr)
#pragma unroll
      for (int fn = 0; fn < 4; ++fn) {
        int vr = n0 - 3072 + wn * 64 + fn * 16 + l16;
        int s0 = m0 + wm * 128 + fr * 16 + quad * 4;
        float b = bv[vr];
        bf16x4 p;
#pragma unroll
        for (int r = 0; r < 4; ++r) p[r] = (__bf16)(acc[fr][fn][r] + b);
        *(bf16x4*)(vto + (size_t)vr * S_LEN + s0) = p;
      }
  }
}

// ---------------------------------------------------------------------------
// Per-head RMSNorm (D=128) + RoPE, in-place on q,k (bf16). One wave/(s,head).
// SCALE*LOG2E folded into q output (log2-domain softmax in attn).
// ---------------------------------------------------------------------------
__global__ __launch_bounds__(256) void rmsnorm_rope(
    __bf16* __restrict__ q, __bf16* __restrict__ k,
    const float* __restrict__ cosb, const float* __restrict__ sinb,
    const float* __restrict__ qw, const float* __restrict__ kw)
{
  const int wave = threadIdx.x >> 6;
  const int lane = threadIdx.x & 63;
  const int row = blockIdx.x * 4 + wave;
  const int s   = row / (NH + KVH);
  const int idx = row % (NH + KVH);

  __bf16* base;
  const float* w;
  float oscale;
  if (idx < NH) { base = q + ((size_t)s * NH + idx) * DH;         w = qw; oscale = SCALE * LOG2E; }
  else          { base = k + ((size_t)s * KVH + (idx - NH)) * DH; w = kw; oscale = 1.0f; }

  float x1 = (float)base[lane];
  float x2 = (float)base[lane + 64];
  float ss = x1 * x1 + x2 * x2;
#pragma unroll
  for (int m = 1; m < 64; m <<= 1) ss += __shfl_xor(ss, m, 64);
  float inv = rsqrtf(ss * (1.0f / 128.0f) + EPS);

  float xh1 = x1 * inv * w[lane];
  float xh2 = x2 * inv * w[lane + 64];
  const float* cs = cosb + (size_t)s * DH;
  const float* sn = sinb + (size_t)s * DH;
  base[lane]      = (__bf16)((xh1 * cs[lane]      - xh2 * sn[lane])      * oscale);
  base[lane + 64] = (__bf16)((xh2 * cs[lane + 64] + xh1 * sn[lane + 64]) * oscale);
}

// ---------------------------------------------------------------------------
// Flash attention v8 = v7 (R6-verified core) + R11 XCD-pinned block mapping.
// R10 counters: FETCH_SIZE 216MB vs ~48MB unique -> K/V re-reads miss L2
// because the 64 blocks sharing one kvh scatter across all 8 XCDs (4MB L2
// each cycles through 16MB of KV). Per-kvh K+V^T = 2MB fits one XCD's L2.
// 1-D grid 512, bijective: kvh = bid&7 (XCD round-robin on linear id, m09),
// j = bid>>3; h = 2*kvh + (j>>5); bx = j&31. Triangle pairing unchanged.
// ---------------------------------------------------------------------------
__global__ __launch_bounds__(256) void attn2(
    const __bf16* __restrict__ q,   // S x NH x DH  (pre-scaled by SCALE*LOG2E)
    const __bf16* __restrict__ k,   // S x KVH x DH
    const __bf16* __restrict__ vt,  // KVH x DH x S
    __bf16* __restrict__ o)         // S x NH x DH
{
  __shared__ __attribute__((aligned(16))) __bf16 Ks[2][64 * DH];  // 32KB swz
  __shared__ __attribute__((aligned(16))) __bf16 Vs[2][DH * 64];  // 32KB swz
  __shared__ __attribute__((aligned(16))) __bf16 pl[4][16 * 72];  // 9KB
  const int wave = threadIdx.x >> 6, lane = threadIdx.x & 63;
  const int quad = lane >> 4, l16 = lane & 15;
  // XCD-pinned decode: blocks of one kvh land on one XCD (2MB KV fits L2).
  const int bid = blockIdx.x;
  const int kvh = bid & 7;
  const int j   = bid >> 3;
  const int h   = kvh * 2 + (j >> 5);
  const int bx  = j & 31;

  const __bf16* kh = k + (size_t)kvh * DH;           // row s at + s*KVH*DH
  const __bf16* vh = vt + (size_t)kvh * DH * S_LEN;  // row d at + d*S_LEN

  // Loop-invariant staging lane offsets (4 K-issues + 4 V-issues per wave).
  int krow[4], kcol[4], vrow[4], vcol[4];
#pragma unroll
  for (int i = 0; i < 4; ++i) {
    int jj = wave + i * 4;
    int r = jj * 4 + (lane >> 4);
    int cbK = ((lane & 15) * 16) ^ ((r & 7) << 4);
    krow[i] = r; kcol[i] = cbK >> 1;
    int d = jj * 8 + (lane >> 3);
    int cbV = ((lane & 7) * 16) ^ ((d & 7) << 4);
    vrow[i] = d; vcol[i] = cbV >> 1;
  }
  auto stage = [&](int buf, int k0) {
#pragma unroll
    for (int i = 0; i < 4; ++i)
      gl_lds16(kh + (size_t)(k0 + krow[i]) * (KVH * DH) + kcol[i],
               &Ks[buf][(wave + i * 4) * 512]);
#pragma unroll
    for (int i = 0; i < 4; ++i)
      gl_lds16(vh + (size_t)vrow[i] * S_LEN + k0 + vcol[i],
               &Vs[buf][(wave + i * 4) * 512]);
  };

  for (int phase = 0; phase < 2; ++phase) {
    const int qt = phase == 0 ? bx : 63 - bx;
    const int qbase = qt * 64 + wave * 16;

    bf16x8 qa[4];
    const __bf16* qrow = q + ((size_t)(qbase + l16) * NH + h) * DH + quad * 8;
#pragma unroll
    for (int c = 0; c < 4; ++c) qa[c] = *(const bf16x8*)(qrow + c * 32);

    f32x4 oacc[8] = {};
    float mrun[4], lrun[4];  // lrun = per-lane PARTIAL row-sum
#pragma unroll
    for (int r = 0; r < 4; ++r) { mrun[r] = -3.0e38f; lrun[r] = 0.0f; }

    __syncthreads();   // prev phase's last reads done before restage
    stage(0, 0);       // prologue

    for (int kt = 0; kt <= qt; ++kt) {
      const int cur = kt & 1;
      const int k0 = kt * 64;
      __syncthreads();
      if (kt < qt) stage(cur ^ 1, k0 + 64);  // prefetch flies over compute

      const char* ksb = (const char*)Ks[cur];
      const char* vsb = (const char*)Vs[cur];

      // ---- scores: 4 col-subtiles x 4 d-chunks (swizzled ds_read) ----
      f32x4 sc[4] = {};
#pragma unroll
      for (int tt = 0; tt < 4; ++tt) {
        const int row = tt * 16 + l16;
        const int swz = (row & 7) << 4;
#pragma unroll
        for (int c = 0; c < 4; ++c) {
          bf16x8 bk = *(const bf16x8*)(ksb + row * 256 + ((c * 64 + quad * 16) ^ swz));
          sc[tt] = __builtin_amdgcn_mfma_f32_16x16x32_bf16(qa[c], bk, sc[tt], 0, 0, 0);
        }
      }
      // ---- causal mask: only the diagonal tile ----
      if (kt == qt) {
#pragma unroll
        for (int tt = 0; tt < 4; ++tt)
#pragma unroll
          for (int r = 0; r < 4; ++r) {
            int col = k0 + tt * 16 + l16;
            int row = qbase + quad * 4 + r;
            if (col > row) sc[tt][r] = -3.0e38f;
          }
      }
      // ---- online softmax (log2 domain): T13 defer-max + deferred l-reduce --
      float pmax[4];
      bool defer = true;
#pragma unroll
      for (int r = 0; r < 4; ++r) {
        float mx = fmaxf(fmaxf(sc[0][r], sc[1][r]), fmaxf(sc[2][r], sc[3][r]));
        pmax[r] = mx;
        defer = defer && (mx - mrun[r] <= 8.0f);
      }
      if (__all(defer)) {
#pragma unroll
        for (int r = 0; r < 4; ++r) {
          float s0 = EXP2(sc[0][r] - mrun[r]);
          float s1 = EXP2(sc[1][r] - mrun[r]);
          float s2 = EXP2(sc[2][r] - mrun[r]);
          float s3 = EXP2(sc[3][r] - mrun[r]);
          sc[0][r] = s0; sc[1][r] = s1; sc[2][r] = s2; sc[3][r] = s3;
          lrun[r] += (s0 + s1) + (s2 + s3);   // per-lane partial
        }
      } else {
#pragma unroll
        for (int r = 0; r < 4; ++r) {
          float mx = pmax[r];
#pragma unroll
          for (int msk = 1; msk < 16; msk <<= 1) mx = fmaxf(mx, __shfl_xor(mx, msk, 64));
          float mnew = fmaxf(mrun[r], mx);     // uniform within 16-lane group
          float sum = 0.0f;
#pragma unroll
          for (int tt = 0; tt < 4; ++tt) {
            float p = EXP2(sc[tt][r] - mnew);
            sc[tt][r] = p;
            sum += p;
          }
          float alpha = EXP2(mrun[r] - mnew);  // uniform -> partial-scale ok
          lrun[r] = lrun[r] * alpha + sum;
          mrun[r] = mnew;
#pragma unroll
          for (int c = 0; c < 8; ++c) oacc[c][r] *= alpha;
        }
      }
      // ---- P: C-layout -> A-layout via per-wave slab (stride 72) ----
#pragma unroll
      for (int tt = 0; tt < 4; ++tt)
#pragma unroll
        for (int r = 0; r < 4; ++r)
          pl[wave][(quad * 4 + r) * 72 + tt * 16 + l16] = (__bf16)sc[tt][r];
      bf16x8 pa[2];
#pragma unroll
      for (int kc = 0; kc < 2; ++kc)
        pa[kc] = *(const bf16x8*)(pl[wave] + l16 * 72 + kc * 32 + quad * 8);
      // ---- PV: 8 d-chunks x 2 k-chunks (swizzled ds_read) ----
#pragma unroll
      for (int c = 0; c < 8; ++c)
#pragma unroll
        for (int kc = 0; kc < 2; ++kc) {
          const int d = c * 16 + l16;
          bf16x8 bv = *(const bf16x8*)(
              vsb + d * 128 + ((kc * 64 + quad * 16) ^ ((d & 7) << 4)));
          oacc[c] = __builtin_amdgcn_mfma_f32_16x16x32_bf16(pa[kc], bv, oacc[c], 0, 0, 0);
        }
    }

    // ---- epilogue: single l-reduce across 16-lane group, then store ----
#pragma unroll
    for (int r = 0; r < 4; ++r) {
#pragma unroll
      for (int msk = 1; msk < 16; msk <<= 1) lrun[r] += __shfl_xor(lrun[r], msk, 64);
      lrun[r] = 1.0f / lrun[r];
    }
#pragma unroll
    for (int c = 0; c < 8; ++c)
#pragma unroll
      for (int r = 0; r < 4; ++r) {
        int row = qbase + quad * 4 + r;
        o[((size_t)row * NH + h) * DH + c * 16 + l16] = (__bf16)(oacc[c][r] * lrun[r]);
      }
  }
}

// ---------------------------------------------------------------------------
extern "C" void kernel_launch(void* const* d_in, const int* in_sizes, int n_in,
                              void* d_out, int out_size, void* d_ws, size_t ws_size,
                              hipStream_t stream) {
  const float* x    = (const float*)d_in[0];
  const float* cosb = (const float*)d_in[1];
  const float* sinb = (const float*)d_in[2];
  // d_in[3] = mask (causal, reimplemented)
  const float* Wq  = (const float*)d_in[4];
  const float* bq  = (const float*)d_in[5];
  const float* Wk  = (const float*)d_in[6];
  const float* bk  = (const float*)d_in[7];
  const float* Wv  = (const float*)d_in[8];
  const float* bv  = (const float*)d_in[9];
  const float* Wo  = (const float*)d_in[10];
  const float* qnw = (const float*)d_in[11];
  const float* knw = (const float*)d_in[12];
  float* out = (float*)d_out;  // 4096x2048 fp32

  // ws (48 MB peak):
  char* ws = (char*)d_ws;
  __bf16* xb    = (__bf16*)(ws);                // 16 MB x bf16 (dies after qkv-GEMM)
  __bf16* Wqb   = (__bf16*)(ws + (16u << 20));  //  8 MB  [Wq;Wk;Wv] contiguous
  __bf16* Wkb   = (__bf16*)(ws + (24u << 20));  //  4 MB  16MB B for fused GEMM
  __bf16* Wvb   = (__bf16*)(ws + (28u << 20));  //  4 MB
  __bf16* kbuf  = (__bf16*)(ws + (32u << 20));  //  8 MB S x KVH x DH
  __bf16* vtbuf = (__bf16*)(ws + (40u << 20));  //  8 MB KVH x DH x S
  __bf16* Wob   = (__bf16*)(ws + (16u << 20));  //  8 MB (reuses Wqb slot)
  __bf16* ao    = (__bf16*)(ws);                // 16 MB attn out (reuses xb slot)
  // d_out doubles as scratch until the final GEMM:
  __bf16* qbuf = (__bf16*)d_out;                // 16 MB S x NH x DH

  dim3 blk(256);
  // merged fp32 -> bf16 converts (x, Wq, Wk, Wv in one launch)
  f2b_all<<<dim3((N4_ALL + 255) / 256), blk, 0, stream>>>(
      x, Wq, Wk, Wv, xb, Wqb, Wkb, Wvb);
  // fused q|k|v GEMM: x @ [Wq;Wk;Wv]^T, 256^2 tiles, 256 blocks = 1/CU exact.
  gemm_qkv256<<<dim3(16, 16), dim3(512), 0, stream>>>(
      xb, Wqb, bq, bk, bv, qbuf, kbuf, vtbuf);
  // rmsnorm + rope (in place; folds SCALE*LOG2E into q)
  rmsnorm_rope<<<dim3(S_LEN * (NH + KVH) / 4), blk, 0, stream>>>(
      qbuf, kbuf, cosb, sinb, qnw, knw);
  // Wo convert into dead Wqb slot (must run after qkv GEMM: aliases Wqb)
  f2b4<<<dim3(4096), blk, 0, stream>>>(Wo, Wob, 1048576);
  // attention -> ao (XCD-pinned 1-D grid)
  attn2<<<dim3(512), blk, 0, stream>>>(qbuf, kbuf, vtbuf, ao);
  // out = ao @ Wo^T  (4096x2048, fp32 epilogue into full d_out)
  gemm128<float><<<dim3(16, 32), blk, 0, stream>>>(ao, Wob, nullptr, out, HID, HID, 0);
}